// Round 1
// baseline (296.631 us; speedup 1.0000x reference)
//
#include <hip/hip_runtime.h>
#include <hip/hip_bf16.h>
#include <stdint.h>

#define HH 80
#define WW 80
#define NQ 6400        // H*W
#define CD 256         // embed dim
#define BB 8
#define OUT_HALF 13107200   // B*C*H*W

typedef __attribute__((ext_vector_type(4))) float f32x4;
typedef __bf16 bf16_t;
typedef __attribute__((ext_vector_type(8))) __bf16 bf16x8;

using gp1_t = const __attribute__((address_space(1))) void*;
using lp3_t = __attribute__((address_space(3))) void*;

__device__ __forceinline__ void gload_lds16(const void* g, void* l) {
    __builtin_amdgcn_global_load_lds((gp1_t)g, (lp3_t)l, 16, 0, 0);
}

// ---------------- PE table: pe[c][n], c<256, n<6400 ----------------
__global__ __launch_bounds__(256) void pe_kernel(float* __restrict__ pe) {
    int idx = blockIdx.x * 256 + threadIdx.x;
    if (idx >= CD * NQ) return;
    int c = idx / NQ, n = idx % NQ;
    int h = n / WW, w = n % WW;
    int k = c >> 2;
    float d = expf((float)(2 * k) * -0.0719557841560639f); // -ln(10000)/128
    float arg = ((c & 2) ? (float)(h + 1) : (float)(w + 1)) * d;
    pe[idx] = (c & 1) ? cosf(arg) : sinf(arg);
}

// ---------------- weight transposes -> bf16, rows = output col, K-contig ----------------
__global__ __launch_bounds__(256) void wprep_kernel(const float* __restrict__ Wv,
                                                    const float* __restrict__ Woff,
                                                    const float* __restrict__ Wattn,
                                                    const float* __restrict__ Wout,
                                                    bf16_t* __restrict__ WvT,
                                                    bf16_t* __restrict__ WoaT,
                                                    bf16_t* __restrict__ WoT) {
    int idx = blockIdx.x * 256 + threadIdx.x;
    if (idx < 65536) {
        int cp = idx >> 8, c = idx & 255;
        WvT[idx] = (bf16_t)Wv[c * 256 + cp];
        WoT[idx] = (bf16_t)Wout[c * 256 + cp];
    }
    if (idx < 96 * 256) {
        int j = idx >> 8, c = idx & 255;
        WoaT[idx] = (bf16_t)(j < 64 ? Woff[c * 64 + j] : Wattn[c * 32 + (j - 64)]);
    }
}

// ---------------- transpose [b][C][NQ] f32 (+pe) -> [b][NQ][C] bf16 ----------------
__global__ __launch_bounds__(256) void xpose_kernel(const float* __restrict__ src,
                                                    const float* __restrict__ pe,
                                                    bf16_t* __restrict__ dst) {
    __shared__ float t[32][33];
    int b = blockIdx.z;
    int n0 = blockIdx.x * 32, c0 = blockIdx.y * 32;
    int tx = threadIdx.x, ty = threadIdx.y;
    const float* s = src + (size_t)b * CD * NQ;
    const bool hasPe = (pe != nullptr);
#pragma unroll
    for (int i = 0; i < 4; i++) {
        int c = c0 + ty + i * 8;
        float v = s[(size_t)c * NQ + n0 + tx];
        if (hasPe) v += pe[c * NQ + n0 + tx];
        t[ty + i * 8][tx] = v;
    }
    __syncthreads();
    bf16_t* d = dst + (size_t)b * NQ * CD;
#pragma unroll
    for (int i = 0; i < 4; i++) {
        int n = n0 + ty + i * 8;
        d[(size_t)n * CD + c0 + tx] = (bf16_t)t[tx][ty + i * 8];
    }
}

// ================= GEMM cores: D = X * Y^T, X=[*][256] bf16, Y=[*][256] bf16 =================
// LDS tiles [rows][64] bf16 (128B rows), XOR-swizzled: LDS[r][j] holds global chunk j^(r&7).
// Staged with linear-dest global_load_lds + inverse-swizzled per-lane global source.

// ---- GEMM1: vproj[n][c'] = value16[n][:] . WvT[c'][:] + b_value[c']  (bf16 out) ----
__global__ __launch_bounds__(256, 2) void gemm_vproj(const bf16_t* __restrict__ X,
                                                     const bf16_t* __restrict__ Y,
                                                     const float* __restrict__ bias,
                                                     bf16_t* __restrict__ D) {
    __shared__ __align__(16) bf16_t lx[128 * 64];
    __shared__ __align__(16) bf16_t ly[128 * 64];
    int m0 = blockIdx.x * 128;   // X rows (n)
    int n0 = blockIdx.y * 128;   // Y rows (c')
    int tid = threadIdx.x, wv = tid >> 6, ln = tid & 63;
    f32x4 acc[4][4] = {};
    int wr = (wv >> 1) * 64, wc = (wv & 1) * 64;
    for (int kt = 0; kt < 4; ++kt) {
#pragma unroll
        for (int q8 = 0; q8 < 4; ++q8) {
            int q = wv * 4 + q8;
            int row = q * 8 + (ln >> 3);
            int jj = (ln & 7) ^ (row & 7);
            gload_lds16((const char*)X + ((size_t)(m0 + row)) * 512 + (size_t)kt * 128 + jj * 16,
                        (char*)lx + q * 1024);
            gload_lds16((const char*)Y + ((size_t)(n0 + row)) * 512 + (size_t)kt * 128 + jj * 16,
                        (char*)ly + q * 1024);
        }
        __syncthreads();
#pragma unroll
        for (int ks = 0; ks < 2; ++ks) {
            bf16x8 xa[4], yb[4];
#pragma unroll
            for (int i = 0; i < 4; i++) {
                int m = wr + i * 16 + (ln & 15);
                int ch = (ks * 4 + (ln >> 4)) ^ (m & 7);
                xa[i] = *(const bf16x8*)((const char*)lx + m * 128 + ch * 16);
                int n = wc + i * 16 + (ln & 15);
                int cn = (ks * 4 + (ln >> 4)) ^ (n & 7);
                yb[i] = *(const bf16x8*)((const char*)ly + n * 128 + cn * 16);
            }
#pragma unroll
            for (int i = 0; i < 4; i++)
#pragma unroll
                for (int j = 0; j < 4; j++)
                    acc[i][j] = __builtin_amdgcn_mfma_f32_16x16x32_bf16(xa[i], yb[j], acc[i][j], 0, 0, 0);
        }
        __syncthreads();
    }
#pragma unroll
    for (int i = 0; i < 4; i++)
#pragma unroll
        for (int j = 0; j < 4; j++) {
            int col = n0 + wc + j * 16 + (ln & 15);
            float bv = bias[col];
#pragma unroll
            for (int rg = 0; rg < 4; rg++) {
                int row = m0 + wr + i * 16 + (ln >> 4) * 4 + rg;
                D[(size_t)row * 256 + col] = (bf16_t)(acc[i][j][rg] + bv);
            }
        }
}

// ---- GEMM2: oa[n][j] = qf16[n][:] . WoaT[j][:] + bias_j  (f32 out, N=96) ----
__global__ __launch_bounds__(256, 2) void gemm_oa(const bf16_t* __restrict__ X,
                                                  const bf16_t* __restrict__ Y,
                                                  const float* __restrict__ boff,
                                                  const float* __restrict__ battn,
                                                  float* __restrict__ D) {
    __shared__ __align__(16) bf16_t lx[128 * 64];
    __shared__ __align__(16) bf16_t ly[96 * 64];
    int m0 = blockIdx.x * 128;
    int tid = threadIdx.x, wv = tid >> 6, ln = tid & 63;
    f32x4 acc[2][6] = {};
    for (int kt = 0; kt < 4; ++kt) {
#pragma unroll
        for (int q8 = 0; q8 < 4; ++q8) {
            int q = wv * 4 + q8;
            int row = q * 8 + (ln >> 3);
            int jj = (ln & 7) ^ (row & 7);
            gload_lds16((const char*)X + ((size_t)(m0 + row)) * 512 + (size_t)kt * 128 + jj * 16,
                        (char*)lx + q * 1024);
        }
#pragma unroll
        for (int q3 = 0; q3 < 3; ++q3) {
            int q = wv * 3 + q3;
            int row = q * 8 + (ln >> 3);
            int jj = (ln & 7) ^ (row & 7);
            gload_lds16((const char*)Y + ((size_t)row) * 512 + (size_t)kt * 128 + jj * 16,
                        (char*)ly + q * 1024);
        }
        __syncthreads();
#pragma unroll
        for (int ks = 0; ks < 2; ++ks) {
            bf16x8 xa[2], yb[6];
#pragma unroll
            for (int i = 0; i < 2; i++) {
                int m = wv * 32 + i * 16 + (ln & 15);
                int ch = (ks * 4 + (ln >> 4)) ^ (m & 7);
                xa[i] = *(const bf16x8*)((const char*)lx + m * 128 + ch * 16);
            }
#pragma unroll
            for (int j = 0; j < 6; j++) {
                int n = j * 16 + (ln & 15);
                int cn = (ks * 4 + (ln >> 4)) ^ (n & 7);
                yb[j] = *(const bf16x8*)((const char*)ly + n * 128 + cn * 16);
            }
#pragma unroll
            for (int i = 0; i < 2; i++)
#pragma unroll
                for (int j = 0; j < 6; j++)
                    acc[i][j] = __builtin_amdgcn_mfma_f32_16x16x32_bf16(xa[i], yb[j], acc[i][j], 0, 0, 0);
        }
        __syncthreads();
    }
#pragma unroll
    for (int i = 0; i < 2; i++)
#pragma unroll
        for (int j = 0; j < 6; j++) {
            int col = j * 16 + (ln & 15);
            float bv = col < 64 ? boff[col] : battn[col - 64];
#pragma unroll
            for (int rg = 0; rg < 4; rg++) {
                int row = m0 + wv * 32 + i * 16 + (ln >> 4) * 4 + rg;
                D[(size_t)row * 96 + col] = acc[i][j][rg] + bv;
            }
        }
}

// ---- sampling: per query block, softmax + bilinear gather, samp[n][c] bf16 ----
__global__ __launch_bounds__(256) void sample_kernel(const float* __restrict__ oa,
                                                     const bf16_t* __restrict__ vp,
                                                     bf16_t* __restrict__ samp) {
    int ng = blockIdx.x;             // 0..51199
    int b = ng / NQ, n = ng % NQ;
    __shared__ float s[96];
    int t = threadIdx.x;
    if (t < 96) s[t] = oa[(size_t)ng * 96 + t];
    __syncthreads();
    int h = t >> 5, hd = t & 31;
    float l0 = s[64 + h * 4 + 0], l1 = s[64 + h * 4 + 1];
    float l2 = s[64 + h * 4 + 2], l3 = s[64 + h * 4 + 3];
    float mx = fmaxf(fmaxf(l0, l1), fmaxf(l2, l3));
    float e0 = expf(l0 - mx), e1 = expf(l1 - mx), e2 = expf(l2 - mx), e3 = expf(l3 - mx);
    float inv = 1.f / (e0 + e1 + e2 + e3);
    float aw[4] = {e0 * inv, e1 * inv, e2 * inv, e3 * inv};
    float refx = (float)(n % WW) * (1.f / 79.f);
    float refy = (float)(n / WW) * (1.f / 79.f);
    const bf16_t* vb = vp + (size_t)b * NQ * CD + h * 32 + hd;
    float acc = 0.f;
#pragma unroll
    for (int p = 0; p < 4; p++) {
        float ox = s[h * 8 + p * 2], oy = s[h * 8 + p * 2 + 1];
        float x = (refx + ox / 80.f) * 80.f - 0.5f;
        float y = (refy + oy / 80.f) * 80.f - 0.5f;
        float x0f = floorf(x), y0f = floorf(y);
        float wx = x - x0f, wy = y - y0f;
        int ix = (int)x0f, iy = (int)y0f;
        float ap = aw[p];
        float w00 = ap * (1.f - wx) * (1.f - wy), w10 = ap * wx * (1.f - wy);
        float w01 = ap * (1.f - wx) * wy,         w11 = ap * wx * wy;
        bool vx0 = (ix >= 0) & (ix < WW),   vx1 = (ix + 1 >= 0) & (ix + 1 < WW);
        bool vy0 = (iy >= 0) & (iy < HH),   vy1 = (iy + 1 >= 0) & (iy + 1 < HH);
        if (vx0 & vy0) acc += w00 * (float)vb[(iy * WW + ix) * CD];
        if (vx1 & vy0) acc += w10 * (float)vb[(iy * WW + ix + 1) * CD];
        if (vx0 & vy1) acc += w01 * (float)vb[((iy + 1) * WW + ix) * CD];
        if (vx1 & vy1) acc += w11 * (float)vb[((iy + 1) * WW + ix + 1) * CD];
    }
    samp[(size_t)ng * CD + t] = (bf16_t)acc;
}

// ---- GEMM3: D[c'][n] = WoT[c'][:] . samp[n][:] ; epilogue: +b_out +query+pe, outputs ----
__global__ __launch_bounds__(256, 2) void gemm_out(const bf16_t* __restrict__ X,   // WoT [256][256]
                                                   const bf16_t* __restrict__ Y,   // samp [51200][256]
                                                   const float* __restrict__ bout,
                                                   const float* __restrict__ query,
                                                   const float* __restrict__ value,
                                                   const float* __restrict__ pe,
                                                   float* __restrict__ out) {
    __shared__ __align__(16) bf16_t lx[128 * 64];
    __shared__ __align__(16) bf16_t ly[128 * 64];
    int m0 = blockIdx.y * 128;   // c'
    int n0 = blockIdx.x * 128;   // n_glob
    int tid = threadIdx.x, wv = tid >> 6, ln = tid & 63;
    f32x4 acc[4][4] = {};
    int wr = (wv >> 1) * 64, wc = (wv & 1) * 64;
    for (int kt = 0; kt < 4; ++kt) {
#pragma unroll
        for (int q8 = 0; q8 < 4; ++q8) {
            int q = wv * 4 + q8;
            int row = q * 8 + (ln >> 3);
            int jj = (ln & 7) ^ (row & 7);
            gload_lds16((const char*)X + ((size_t)(m0 + row)) * 512 + (size_t)kt * 128 + jj * 16,
                        (char*)lx + q * 1024);
            gload_lds16((const char*)Y + ((size_t)(n0 + row)) * 512 + (size_t)kt * 128 + jj * 16,
                        (char*)ly + q * 1024);
        }
        __syncthreads();
#pragma unroll
        for (int ks = 0; ks < 2; ++ks) {
            bf16x8 xa[4], yb[4];
#pragma unroll
            for (int i = 0; i < 4; i++) {
                int m = wr + i * 16 + (ln & 15);
                int ch = (ks * 4 + (ln >> 4)) ^ (m & 7);
                xa[i] = *(const bf16x8*)((const char*)lx + m * 128 + ch * 16);
                int n = wc + i * 16 + (ln & 15);
                int cn = (ks * 4 + (ln >> 4)) ^ (n & 7);
                yb[i] = *(const bf16x8*)((const char*)ly + n * 128 + cn * 16);
            }
#pragma unroll
            for (int i = 0; i < 4; i++)
#pragma unroll
                for (int j = 0; j < 4; j++)
                    acc[i][j] = __builtin_amdgcn_mfma_f32_16x16x32_bf16(xa[i], yb[j], acc[i][j], 0, 0, 0);
        }
        __syncthreads();
    }
    int b = n0 / NQ;
    int nb = n0 - b * NQ;
    const float* q = query + (size_t)b * CD * NQ;
    const float* v = value + (size_t)b * CD * NQ;
    float* o0 = out + (size_t)b * CD * NQ;
    float* o1 = out + OUT_HALF + (size_t)b * CD * NQ;
#pragma unroll
    for (int i = 0; i < 4; i++)
#pragma unroll
        for (int j = 0; j < 4; j++) {
            int n = nb + wc + j * 16 + (ln & 15);
#pragma unroll
            for (int rg = 0; rg < 4; rg++) {
                int row = m0 + wr + i * 16 + (ln >> 4) * 4 + rg;
                size_t off = (size_t)row * NQ + n;
                float tv = acc[i][j][rg] + bout[row] + q[off] + pe[off];
                o1[off] = tv;
                o0[off] = tv + v[off];
            }
        }
}

extern "C" void kernel_launch(void* const* d_in, const int* in_sizes, int n_in,
                              void* d_out, int out_size, void* d_ws, size_t ws_size,
                              hipStream_t stream) {
    const float* query   = (const float*)d_in[0];
    const float* value   = (const float*)d_in[1];
    const float* W_value = (const float*)d_in[2];
    const float* b_value = (const float*)d_in[3];
    const float* W_off   = (const float*)d_in[4];
    const float* b_off   = (const float*)d_in[5];
    const float* W_attn  = (const float*)d_in[6];
    const float* b_attn  = (const float*)d_in[7];
    const float* W_out   = (const float*)d_in[8];
    const float* b_out   = (const float*)d_in[9];
    float* out = (float*)d_out;
    char* ws = (char*)d_ws;

    float*  pe    = (float*)(ws + 0);              //  6,553,600
    bf16_t* vb16  = (bf16_t*)(ws + 6553600);       // 26,214,400
    bf16_t* qb16  = (bf16_t*)(ws + 32768000);      // 26,214,400
    bf16_t* WvT   = (bf16_t*)(ws + 58982400);      //    131,072
    bf16_t* WoT   = (bf16_t*)(ws + 59113472);      //    131,072
    bf16_t* WoaT  = (bf16_t*)(ws + 59244544);      //     49,152
    bf16_t* vproj = (bf16_t*)(ws + 59293696);      // 26,214,400
    float*  oa    = (float*)(ws + 85508096);       // 19,660,800
    bf16_t* samp  = (bf16_t*)(ws + 105168896);     // 26,214,400  (total ~131.4 MB)

    pe_kernel<<<(CD * NQ + 255) / 256, 256, 0, stream>>>(pe);
    wprep_kernel<<<256, 256, 0, stream>>>(W_value, W_off, W_attn, W_out, WvT, WoaT, WoT);
    dim3 tb(32, 8);
    xpose_kernel<<<dim3(200, 8, BB), tb, 0, stream>>>(value, nullptr, vb16);
    xpose_kernel<<<dim3(200, 8, BB), tb, 0, stream>>>(query, pe, qb16);
    gemm_vproj<<<dim3(400, 2), 256, 0, stream>>>(vb16, WvT, b_value, vproj);
    gemm_oa<<<dim3(400), 256, 0, stream>>>(qb16, WoaT, b_off, b_attn, oa);
    sample_kernel<<<BB * NQ, 256, 0, stream>>>(oa, vproj, samp);
    gemm_out<<<dim3(400, 2), 256, 0, stream>>>(WoT, samp, b_out, query, value, pe, out);
}

// Round 2
// 184.644 us; speedup vs baseline: 1.6065x; 1.6065x over previous
//
#include <hip/hip_runtime.h>
#include <hip/hip_bf16.h>
#include <stdint.h>

#define HH 80
#define WW 80
#define NQ 6400        // H*W
#define CD 256         // embed dim
#define BB 8
#define OUT_HALF 13107200   // B*C*H*W

typedef __attribute__((ext_vector_type(4))) float f32x4;
typedef __bf16 bf16_t;
typedef __attribute__((ext_vector_type(8))) __bf16 bf16x8;
typedef __attribute__((ext_vector_type(4))) __bf16 bf16x4;

using gp1_t = const __attribute__((address_space(1))) void*;
using lp3_t = __attribute__((address_space(3))) void*;

__device__ __forceinline__ void gload_lds16(const void* g, void* l) {
    __builtin_amdgcn_global_load_lds((gp1_t)g, (lp3_t)l, 16, 0, 0);
}

// ---------------- PE table: pe[c][n], c<256, n<6400 ----------------
__global__ __launch_bounds__(256) void pe_kernel(float* __restrict__ pe) {
    int idx = blockIdx.x * 256 + threadIdx.x;
    if (idx >= CD * NQ) return;
    int c = idx / NQ, n = idx % NQ;
    int h = n / WW, w = n % WW;
    int k = c >> 2;
    float d = expf((float)(2 * k) * -0.0719557841560639f); // -ln(10000)/128
    float arg = ((c & 2) ? (float)(h + 1) : (float)(w + 1)) * d;
    pe[idx] = (c & 1) ? cosf(arg) : sinf(arg);
}

// ---------------- weight transposes -> bf16, rows = output col, K-contig ----------------
__global__ __launch_bounds__(256) void wprep_kernel(const float* __restrict__ Wv,
                                                    const float* __restrict__ Woff,
                                                    const float* __restrict__ Wattn,
                                                    const float* __restrict__ Wout,
                                                    bf16_t* __restrict__ WvT,
                                                    bf16_t* __restrict__ WoaT,
                                                    bf16_t* __restrict__ WoT) {
    int idx = blockIdx.x * 256 + threadIdx.x;
    if (idx < 65536) {
        int cp = idx >> 8, c = idx & 255;
        WvT[idx] = (bf16_t)Wv[c * 256 + cp];
        WoT[idx] = (bf16_t)Wout[c * 256 + cp];
    }
    if (idx < 96 * 256) {
        int j = idx >> 8, c = idx & 255;
        WoaT[idx] = (bf16_t)(j < 64 ? Woff[c * 64 + j] : Wattn[c * 32 + (j - 64)]);
    }
}

// ---------------- transpose [b][C][NQ] f32 (+pe) -> [b][NQ][C] bf16 ----------------
__global__ __launch_bounds__(256) void xpose_kernel(const float* __restrict__ src,
                                                    const float* __restrict__ pe,
                                                    bf16_t* __restrict__ dst) {
    __shared__ float t[32][33];
    int b = blockIdx.z;
    int n0 = blockIdx.x * 32, c0 = blockIdx.y * 32;
    int tx = threadIdx.x, ty = threadIdx.y;
    const float* s = src + (size_t)b * CD * NQ;
    const bool hasPe = (pe != nullptr);
#pragma unroll
    for (int i = 0; i < 4; i++) {
        int c = c0 + ty + i * 8;
        float v = s[(size_t)c * NQ + n0 + tx];
        if (hasPe) v += pe[c * NQ + n0 + tx];
        t[ty + i * 8][tx] = v;
    }
    __syncthreads();
    bf16_t* d = dst + (size_t)b * NQ * CD;
#pragma unroll
    for (int i = 0; i < 4; i++) {
        int n = n0 + ty + i * 8;
        d[(size_t)n * CD + c0 + tx] = (bf16_t)t[tx][ty + i * 8];
    }
}

// ================= GEMM cores: D = X * Y^T, X=[*][256] bf16, Y=[*][256] bf16 =================
// LDS tiles [rows][64] bf16 (128B rows), XOR-swizzled: LDS[r][j] holds global chunk j^(r&7).

// ---- GEMM1: vproj[n][c'] = value16[n][:] . WvT[c'][:] + b_value[c']  (f32 out for sampler) ----
__global__ __launch_bounds__(256, 2) void gemm_vproj(const bf16_t* __restrict__ X,
                                                     const bf16_t* __restrict__ Y,
                                                     const float* __restrict__ bias,
                                                     float* __restrict__ D) {
    __shared__ __align__(16) bf16_t lx[128 * 64];
    __shared__ __align__(16) bf16_t ly[128 * 64];
    int m0 = blockIdx.x * 128;   // X rows (n)
    int n0 = blockIdx.y * 128;   // Y rows (c')
    int tid = threadIdx.x, wv = tid >> 6, ln = tid & 63;
    f32x4 acc[4][4] = {};
    int wr = (wv >> 1) * 64, wc = (wv & 1) * 64;
    for (int kt = 0; kt < 4; ++kt) {
#pragma unroll
        for (int q8 = 0; q8 < 4; ++q8) {
            int q = wv * 4 + q8;
            int row = q * 8 + (ln >> 3);
            int jj = (ln & 7) ^ (row & 7);
            gload_lds16((const char*)X + ((size_t)(m0 + row)) * 512 + (size_t)kt * 128 + jj * 16,
                        (char*)lx + q * 1024);
            gload_lds16((const char*)Y + ((size_t)(n0 + row)) * 512 + (size_t)kt * 128 + jj * 16,
                        (char*)ly + q * 1024);
        }
        __syncthreads();
#pragma unroll
        for (int ks = 0; ks < 2; ++ks) {
            bf16x8 xa[4], yb[4];
#pragma unroll
            for (int i = 0; i < 4; i++) {
                int m = wr + i * 16 + (ln & 15);
                int ch = (ks * 4 + (ln >> 4)) ^ (m & 7);
                xa[i] = *(const bf16x8*)((const char*)lx + m * 128 + ch * 16);
                int n = wc + i * 16 + (ln & 15);
                int cn = (ks * 4 + (ln >> 4)) ^ (n & 7);
                yb[i] = *(const bf16x8*)((const char*)ly + n * 128 + cn * 16);
            }
#pragma unroll
            for (int i = 0; i < 4; i++)
#pragma unroll
                for (int j = 0; j < 4; j++)
                    acc[i][j] = __builtin_amdgcn_mfma_f32_16x16x32_bf16(xa[i], yb[j], acc[i][j], 0, 0, 0);
        }
        __syncthreads();
    }
#pragma unroll
    for (int i = 0; i < 4; i++)
#pragma unroll
        for (int j = 0; j < 4; j++) {
            int col = n0 + wc + j * 16 + (ln & 15);
            float bv = bias[col];
#pragma unroll
            for (int rg = 0; rg < 4; rg++) {
                int row = m0 + wr + i * 16 + (ln >> 4) * 4 + rg;
                D[(size_t)row * 256 + col] = acc[i][j][rg] + bv;
            }
        }
}

// ---- GEMM2: oa[n][j] = qf16[n][:] . WoaT[j][:] + bias_j  (f32 out, N=96) ----
__global__ __launch_bounds__(256, 2) void gemm_oa(const bf16_t* __restrict__ X,
                                                  const bf16_t* __restrict__ Y,
                                                  const float* __restrict__ boff,
                                                  const float* __restrict__ battn,
                                                  float* __restrict__ D) {
    __shared__ __align__(16) bf16_t lx[128 * 64];
    __shared__ __align__(16) bf16_t ly[96 * 64];
    int m0 = blockIdx.x * 128;
    int tid = threadIdx.x, wv = tid >> 6, ln = tid & 63;
    f32x4 acc[2][6] = {};
    for (int kt = 0; kt < 4; ++kt) {
#pragma unroll
        for (int q8 = 0; q8 < 4; ++q8) {
            int q = wv * 4 + q8;
            int row = q * 8 + (ln >> 3);
            int jj = (ln & 7) ^ (row & 7);
            gload_lds16((const char*)X + ((size_t)(m0 + row)) * 512 + (size_t)kt * 128 + jj * 16,
                        (char*)lx + q * 1024);
        }
#pragma unroll
        for (int q3 = 0; q3 < 3; ++q3) {
            int q = wv * 3 + q3;
            int row = q * 8 + (ln >> 3);
            int jj = (ln & 7) ^ (row & 7);
            gload_lds16((const char*)Y + ((size_t)row) * 512 + (size_t)kt * 128 + jj * 16,
                        (char*)ly + q * 1024);
        }
        __syncthreads();
#pragma unroll
        for (int ks = 0; ks < 2; ++ks) {
            bf16x8 xa[2], yb[6];
#pragma unroll
            for (int i = 0; i < 2; i++) {
                int m = wv * 32 + i * 16 + (ln & 15);
                int ch = (ks * 4 + (ln >> 4)) ^ (m & 7);
                xa[i] = *(const bf16x8*)((const char*)lx + m * 128 + ch * 16);
            }
#pragma unroll
            for (int j = 0; j < 6; j++) {
                int n = j * 16 + (ln & 15);
                int cn = (ks * 4 + (ln >> 4)) ^ (n & 7);
                yb[j] = *(const bf16x8*)((const char*)ly + n * 128 + cn * 16);
            }
#pragma unroll
            for (int i = 0; i < 2; i++)
#pragma unroll
                for (int j = 0; j < 6; j++)
                    acc[i][j] = __builtin_amdgcn_mfma_f32_16x16x32_bf16(xa[i], yb[j], acc[i][j], 0, 0, 0);
        }
        __syncthreads();
    }
#pragma unroll
    for (int i = 0; i < 2; i++)
#pragma unroll
        for (int j = 0; j < 6; j++) {
            int col = j * 16 + (ln & 15);
            float bv = col < 64 ? boff[col] : battn[col - 64];
#pragma unroll
            for (int rg = 0; rg < 4; rg++) {
                int row = m0 + wv * 32 + i * 16 + (ln >> 4) * 4 + rg;
                D[(size_t)row * 96 + col] = acc[i][j][rg] + bv;
            }
        }
}

// ---- sampling v2: 4 queries/block. Phase1 (32 thr): softmax+weights+indices once per (q,h)
//      into LDS. Phase2 (256 thr): branch-free float4 gather, 4 channels/thread. ----
__global__ __launch_bounds__(256) void sample_kernel(const float* __restrict__ oa,
                                                     const float* __restrict__ vp,
                                                     bf16_t* __restrict__ samp) {
    __shared__ float2 swo[4][8][17];   // [q][h][p*4+corner] = {weight, bits(index)}, padded
    int t = threadIdx.x;
    int q0 = blockIdx.x * 4;           // NQ%4==0 -> block never straddles batches
    if (t < 32) {
        int q = t >> 3, h = t & 7;
        int ng = q0 + q;
        int n = ng % NQ;
        const float* s = oa + (size_t)ng * 96;
        float l0 = s[64 + h * 4 + 0], l1 = s[64 + h * 4 + 1];
        float l2 = s[64 + h * 4 + 2], l3 = s[64 + h * 4 + 3];
        float mx = fmaxf(fmaxf(l0, l1), fmaxf(l2, l3));
        float e0 = expf(l0 - mx), e1 = expf(l1 - mx), e2 = expf(l2 - mx), e3 = expf(l3 - mx);
        float inv = 1.f / (e0 + e1 + e2 + e3);
        float aw[4] = {e0 * inv, e1 * inv, e2 * inv, e3 * inv};
        float xb = (float)(n % WW) * (80.f / 79.f) - 0.5f;
        float yb = (float)(n / WW) * (80.f / 79.f) - 0.5f;
#pragma unroll
        for (int p = 0; p < 4; p++) {
            float x = xb + s[h * 8 + p * 2];
            float y = yb + s[h * 8 + p * 2 + 1];
            float x0f = floorf(x), y0f = floorf(y);
            float wx = x - x0f, wy = y - y0f;
            int ix = (int)x0f, iy = (int)y0f;
            bool vx0 = (unsigned)ix < (unsigned)WW, vx1 = (unsigned)(ix + 1) < (unsigned)WW;
            bool vy0 = (unsigned)iy < (unsigned)HH, vy1 = (unsigned)(iy + 1) < (unsigned)HH;
            int cx0 = min(max(ix, 0), WW - 1), cx1 = min(max(ix + 1, 0), WW - 1);
            int cy0 = min(max(iy, 0), HH - 1), cy1 = min(max(iy + 1, 0), HH - 1);
            float ap = aw[p];
            float w00 = (vx0 && vy0) ? ap * (1.f - wx) * (1.f - wy) : 0.f;
            float w10 = (vx1 && vy0) ? ap * wx * (1.f - wy) : 0.f;
            float w01 = (vx0 && vy1) ? ap * (1.f - wx) * wy : 0.f;
            float w11 = (vx1 && vy1) ? ap * wx * wy : 0.f;
            swo[q][h][p * 4 + 0] = make_float2(w00, __int_as_float(cy0 * WW + cx0));
            swo[q][h][p * 4 + 1] = make_float2(w10, __int_as_float(cy0 * WW + cx1));
            swo[q][h][p * 4 + 2] = make_float2(w01, __int_as_float(cy1 * WW + cx0));
            swo[q][h][p * 4 + 3] = make_float2(w11, __int_as_float(cy1 * WW + cx1));
        }
    }
    __syncthreads();
    int q = t >> 6, h = (t >> 3) & 7, cg = t & 7;
    int ng = q0 + q;
    int b = ng / NQ;
    const float* vb = vp + (size_t)b * NQ * CD + h * 32 + cg * 4;
    f32x4 acc = {0.f, 0.f, 0.f, 0.f};
#pragma unroll
    for (int pc = 0; pc < 16; ++pc) {
        float2 wo = swo[q][h][pc];
        int off = __float_as_int(wo.y);
        f32x4 v = *(const f32x4*)(vb + (size_t)off * CD);
        acc += v * wo.x;
    }
    bf16x4 ov;
    ov[0] = (bf16_t)acc[0]; ov[1] = (bf16_t)acc[1];
    ov[2] = (bf16_t)acc[2]; ov[3] = (bf16_t)acc[3];
    *(bf16x4*)(samp + (size_t)ng * CD + h * 32 + cg * 4) = ov;
}

// ---- GEMM3: D[c'][n] = WoT[c'][:] . samp[n][:] ; epilogue: +b_out +query+pe, outputs ----
__global__ __launch_bounds__(256, 2) void gemm_out(const bf16_t* __restrict__ X,   // WoT [256][256]
                                                   const bf16_t* __restrict__ Y,   // samp [51200][256]
                                                   const float* __restrict__ bout,
                                                   const float* __restrict__ query,
                                                   const float* __restrict__ value,
                                                   const float* __restrict__ pe,
                                                   float* __restrict__ out) {
    __shared__ __align__(16) bf16_t lx[128 * 64];
    __shared__ __align__(16) bf16_t ly[128 * 64];
    int m0 = blockIdx.y * 128;   // c'
    int n0 = blockIdx.x * 128;   // n_glob
    int tid = threadIdx.x, wv = tid >> 6, ln = tid & 63;
    f32x4 acc[4][4] = {};
    int wr = (wv >> 1) * 64, wc = (wv & 1) * 64;
    for (int kt = 0; kt < 4; ++kt) {
#pragma unroll
        for (int q8 = 0; q8 < 4; ++q8) {
            int q = wv * 4 + q8;
            int row = q * 8 + (ln >> 3);
            int jj = (ln & 7) ^ (row & 7);
            gload_lds16((const char*)X + ((size_t)(m0 + row)) * 512 + (size_t)kt * 128 + jj * 16,
                        (char*)lx + q * 1024);
            gload_lds16((const char*)Y + ((size_t)(n0 + row)) * 512 + (size_t)kt * 128 + jj * 16,
                        (char*)ly + q * 1024);
        }
        __syncthreads();
#pragma unroll
        for (int ks = 0; ks < 2; ++ks) {
            bf16x8 xa[4], yb[4];
#pragma unroll
            for (int i = 0; i < 4; i++) {
                int m = wr + i * 16 + (ln & 15);
                int ch = (ks * 4 + (ln >> 4)) ^ (m & 7);
                xa[i] = *(const bf16x8*)((const char*)lx + m * 128 + ch * 16);
                int n = wc + i * 16 + (ln & 15);
                int cn = (ks * 4 + (ln >> 4)) ^ (n & 7);
                yb[i] = *(const bf16x8*)((const char*)ly + n * 128 + cn * 16);
            }
#pragma unroll
            for (int i = 0; i < 4; i++)
#pragma unroll
                for (int j = 0; j < 4; j++)
                    acc[i][j] = __builtin_amdgcn_mfma_f32_16x16x32_bf16(xa[i], yb[j], acc[i][j], 0, 0, 0);
        }
        __syncthreads();
    }
    int b = n0 / NQ;
    int nb = n0 - b * NQ;
    const float* q = query + (size_t)b * CD * NQ;
    const float* v = value + (size_t)b * CD * NQ;
    float* o0 = out + (size_t)b * CD * NQ;
    float* o1 = out + OUT_HALF + (size_t)b * CD * NQ;
#pragma unroll
    for (int i = 0; i < 4; i++)
#pragma unroll
        for (int j = 0; j < 4; j++) {
            int n = nb + wc + j * 16 + (ln & 15);
#pragma unroll
            for (int rg = 0; rg < 4; rg++) {
                int row = m0 + wr + i * 16 + (ln >> 4) * 4 + rg;
                size_t off = (size_t)row * NQ + n;
                float tv = acc[i][j][rg] + bout[row] + q[off] + pe[off];
                o1[off] = tv;
                o0[off] = tv + v[off];
            }
        }
}

extern "C" void kernel_launch(void* const* d_in, const int* in_sizes, int n_in,
                              void* d_out, int out_size, void* d_ws, size_t ws_size,
                              hipStream_t stream) {
    const float* query   = (const float*)d_in[0];
    const float* value   = (const float*)d_in[1];
    const float* W_value = (const float*)d_in[2];
    const float* b_value = (const float*)d_in[3];
    const float* W_off   = (const float*)d_in[4];
    const float* b_off   = (const float*)d_in[5];
    const float* W_attn  = (const float*)d_in[6];
    const float* b_attn  = (const float*)d_in[7];
    const float* W_out   = (const float*)d_in[8];
    const float* b_out   = (const float*)d_in[9];
    float* out = (float*)d_out;
    char* ws = (char*)d_ws;

    float*  pe    = (float*)(ws + 0);              //  6,553,600
    bf16_t* vb16  = (bf16_t*)(ws + 6553600);       // 26,214,400 (dead after gemm_vproj)
    bf16_t* samp  = (bf16_t*)(ws + 6553600);       //   aliases vb16
    bf16_t* qb16  = (bf16_t*)(ws + 32768000);      // 26,214,400
    bf16_t* WvT   = (bf16_t*)(ws + 58982400);      //    131,072
    bf16_t* WoT   = (bf16_t*)(ws + 59113472);      //    131,072
    bf16_t* WoaT  = (bf16_t*)(ws + 59244544);      //     49,152
    float*  vprojF= (float*)(ws + 59293696);       // 52,428,800
    float*  oa    = (float*)(ws + 111722496);      // 19,660,800  (total ~131.4 MB)

    pe_kernel<<<(CD * NQ + 255) / 256, 256, 0, stream>>>(pe);
    wprep_kernel<<<256, 256, 0, stream>>>(W_value, W_off, W_attn, W_out, WvT, WoaT, WoT);
    dim3 tb(32, 8);
    xpose_kernel<<<dim3(200, 8, BB), tb, 0, stream>>>(value, nullptr, vb16);
    xpose_kernel<<<dim3(200, 8, BB), tb, 0, stream>>>(query, pe, qb16);
    gemm_vproj<<<dim3(400, 2), 256, 0, stream>>>(vb16, WvT, b_value, vprojF);
    gemm_oa<<<dim3(400), 256, 0, stream>>>(qb16, WoaT, b_off, b_attn, oa);
    sample_kernel<<<BB * NQ / 4, 256, 0, stream>>>(oa, vprojF, samp);
    gemm_out<<<dim3(400, 2), 256, 0, stream>>>(WoT, samp, b_out, query, value, pe, out);
}

// Round 3
// 149.376 us; speedup vs baseline: 1.9858x; 1.2361x over previous
//
#include <hip/hip_runtime.h>
#include <hip/hip_bf16.h>
#include <stdint.h>

#define HH 80
#define WW 80
#define NQ 6400        // H*W
#define CD 256         // embed dim
#define BB 8
#define OUT_HALF 13107200   // B*C*H*W

typedef __attribute__((ext_vector_type(4))) float f32x4;
typedef __bf16 bf16_t;
typedef __attribute__((ext_vector_type(8))) __bf16 bf16x8;
typedef __attribute__((ext_vector_type(4))) __bf16 bf16x4;

using gp1_t = const __attribute__((address_space(1))) void*;
using lp3_t = __attribute__((address_space(3))) void*;

__device__ __forceinline__ void gload_lds16(const void* g, void* l) {
    __builtin_amdgcn_global_load_lds((gp1_t)g, (lp3_t)l, 16, 0, 0);
}

// ---------------- PE table: pe[c][n], c<256, n<6400 ----------------
__global__ __launch_bounds__(256) void pe_kernel(float* __restrict__ pe) {
    int idx = blockIdx.x * 256 + threadIdx.x;
    if (idx >= CD * NQ) return;
    int c = idx / NQ, n = idx % NQ;
    int h = n / WW, w = n % WW;
    int k = c >> 2;
    float d = expf((float)(2 * k) * -0.0719557841560639f); // -ln(10000)/128
    float arg = ((c & 2) ? (float)(h + 1) : (float)(w + 1)) * d;
    pe[idx] = (c & 1) ? cosf(arg) : sinf(arg);
}

// ---------------- weight transposes -> bf16, rows = output col, K-contig ----------------
__global__ __launch_bounds__(256) void wprep_kernel(const float* __restrict__ Wv,
                                                    const float* __restrict__ Woff,
                                                    const float* __restrict__ Wattn,
                                                    const float* __restrict__ Wout,
                                                    bf16_t* __restrict__ WvT,
                                                    bf16_t* __restrict__ WoaT,
                                                    bf16_t* __restrict__ WoT) {
    int idx = blockIdx.x * 256 + threadIdx.x;
    if (idx < 65536) {
        int cp = idx >> 8, c = idx & 255;
        WvT[idx] = (bf16_t)Wv[c * 256 + cp];
        WoT[idx] = (bf16_t)Wout[c * 256 + cp];
    }
    if (idx < 96 * 256) {
        int j = idx >> 8, c = idx & 255;
        WoaT[idx] = (bf16_t)(j < 64 ? Woff[c * 64 + j] : Wattn[c * 32 + (j - 64)]);
    }
}

// ---------------- transpose [b][C][NQ] f32 (+pe) -> [b][NQ][C] bf16 ----------------
__global__ __launch_bounds__(256) void xpose_kernel(const float* __restrict__ src,
                                                    const float* __restrict__ pe,
                                                    bf16_t* __restrict__ dst) {
    __shared__ float t[32][33];
    int b = blockIdx.z;
    int n0 = blockIdx.x * 32, c0 = blockIdx.y * 32;
    int tx = threadIdx.x, ty = threadIdx.y;
    const float* s = src + (size_t)b * CD * NQ;
    const bool hasPe = (pe != nullptr);
#pragma unroll
    for (int i = 0; i < 4; i++) {
        int c = c0 + ty + i * 8;
        float v = s[(size_t)c * NQ + n0 + tx];
        if (hasPe) v += pe[c * NQ + n0 + tx];
        t[ty + i * 8][tx] = v;
    }
    __syncthreads();
    bf16_t* d = dst + (size_t)b * NQ * CD;
#pragma unroll
    for (int i = 0; i < 4; i++) {
        int n = n0 + ty + i * 8;
        d[(size_t)n * CD + c0 + tx] = (bf16_t)t[tx][ty + i * 8];
    }
}

// ================= GEMM cores: D = X * Y^T, X=[*][256] bf16, Y=[*][256] bf16 =================
// LDS tiles [rows][64] bf16 (128B rows), XOR-swizzled: LDS[r][j] holds global chunk j^(r&7).

// ---- GEMM1: vproj[n][c'] = value16[n][:] . WvT[c'][:] + b_value[c']  (bf16 out) ----
__global__ __launch_bounds__(256, 2) void gemm_vproj(const bf16_t* __restrict__ X,
                                                     const bf16_t* __restrict__ Y,
                                                     const float* __restrict__ bias,
                                                     bf16_t* __restrict__ D) {
    __shared__ __align__(16) bf16_t lx[128 * 64];
    __shared__ __align__(16) bf16_t ly[128 * 64];
    int m0 = blockIdx.x * 128;   // X rows (n)
    int n0 = blockIdx.y * 128;   // Y rows (c')
    int tid = threadIdx.x, wv = tid >> 6, ln = tid & 63;
    f32x4 acc[4][4] = {};
    int wr = (wv >> 1) * 64, wc = (wv & 1) * 64;
    for (int kt = 0; kt < 4; ++kt) {
#pragma unroll
        for (int q8 = 0; q8 < 4; ++q8) {
            int q = wv * 4 + q8;
            int row = q * 8 + (ln >> 3);
            int jj = (ln & 7) ^ (row & 7);
            gload_lds16((const char*)X + ((size_t)(m0 + row)) * 512 + (size_t)kt * 128 + jj * 16,
                        (char*)lx + q * 1024);
            gload_lds16((const char*)Y + ((size_t)(n0 + row)) * 512 + (size_t)kt * 128 + jj * 16,
                        (char*)ly + q * 1024);
        }
        __syncthreads();
#pragma unroll
        for (int ks = 0; ks < 2; ++ks) {
            bf16x8 xa[4], yb[4];
#pragma unroll
            for (int i = 0; i < 4; i++) {
                int m = wr + i * 16 + (ln & 15);
                int ch = (ks * 4 + (ln >> 4)) ^ (m & 7);
                xa[i] = *(const bf16x8*)((const char*)lx + m * 128 + ch * 16);
                int n = wc + i * 16 + (ln & 15);
                int cn = (ks * 4 + (ln >> 4)) ^ (n & 7);
                yb[i] = *(const bf16x8*)((const char*)ly + n * 128 + cn * 16);
            }
#pragma unroll
            for (int i = 0; i < 4; i++)
#pragma unroll
                for (int j = 0; j < 4; j++)
                    acc[i][j] = __builtin_amdgcn_mfma_f32_16x16x32_bf16(xa[i], yb[j], acc[i][j], 0, 0, 0);
        }
        __syncthreads();
    }
#pragma unroll
    for (int i = 0; i < 4; i++)
#pragma unroll
        for (int j = 0; j < 4; j++) {
            int col = n0 + wc + j * 16 + (ln & 15);
            float bv = bias[col];
#pragma unroll
            for (int rg = 0; rg < 4; rg++) {
                int row = m0 + wr + i * 16 + (ln >> 4) * 4 + rg;
                D[(size_t)row * 256 + col] = (bf16_t)(acc[i][j][rg] + bv);
            }
        }
}

// ---- GEMM2: oa[n][j] = qf16[n][:] . WoaT[j][:] + bias_j  (f32 out, N=96) ----
__global__ __launch_bounds__(256, 2) void gemm_oa(const bf16_t* __restrict__ X,
                                                  const bf16_t* __restrict__ Y,
                                                  const float* __restrict__ boff,
                                                  const float* __restrict__ battn,
                                                  float* __restrict__ D) {
    __shared__ __align__(16) bf16_t lx[128 * 64];
    __shared__ __align__(16) bf16_t ly[96 * 64];
    int m0 = blockIdx.x * 128;
    int tid = threadIdx.x, wv = tid >> 6, ln = tid & 63;
    f32x4 acc[2][6] = {};
    for (int kt = 0; kt < 4; ++kt) {
#pragma unroll
        for (int q8 = 0; q8 < 4; ++q8) {
            int q = wv * 4 + q8;
            int row = q * 8 + (ln >> 3);
            int jj = (ln & 7) ^ (row & 7);
            gload_lds16((const char*)X + ((size_t)(m0 + row)) * 512 + (size_t)kt * 128 + jj * 16,
                        (char*)lx + q * 1024);
        }
#pragma unroll
        for (int q3 = 0; q3 < 3; ++q3) {
            int q = wv * 3 + q3;
            int row = q * 8 + (ln >> 3);
            int jj = (ln & 7) ^ (row & 7);
            gload_lds16((const char*)Y + ((size_t)row) * 512 + (size_t)kt * 128 + jj * 16,
                        (char*)ly + q * 1024);
        }
        __syncthreads();
#pragma unroll
        for (int ks = 0; ks < 2; ++ks) {
            bf16x8 xa[2], yb[6];
#pragma unroll
            for (int i = 0; i < 2; i++) {
                int m = wv * 32 + i * 16 + (ln & 15);
                int ch = (ks * 4 + (ln >> 4)) ^ (m & 7);
                xa[i] = *(const bf16x8*)((const char*)lx + m * 128 + ch * 16);
            }
#pragma unroll
            for (int j = 0; j < 6; j++) {
                int n = j * 16 + (ln & 15);
                int cn = (ks * 4 + (ln >> 4)) ^ (n & 7);
                yb[j] = *(const bf16x8*)((const char*)ly + n * 128 + cn * 16);
            }
#pragma unroll
            for (int i = 0; i < 2; i++)
#pragma unroll
                for (int j = 0; j < 6; j++)
                    acc[i][j] = __builtin_amdgcn_mfma_f32_16x16x32_bf16(xa[i], yb[j], acc[i][j], 0, 0, 0);
        }
        __syncthreads();
    }
#pragma unroll
    for (int i = 0; i < 2; i++)
#pragma unroll
        for (int j = 0; j < 6; j++) {
            int col = j * 16 + (ln & 15);
            float bv = col < 64 ? boff[col] : battn[col - 64];
#pragma unroll
            for (int rg = 0; rg < 4; rg++) {
                int row = m0 + wv * 32 + i * 16 + (ln >> 4) * 4 + rg;
                D[(size_t)row * 96 + col] = acc[i][j][rg] + bv;
            }
        }
}

// ---- sampling: 4 queries/block. Phase1 (32 thr): softmax+weights+indices per (q,h) into LDS.
//      Phase2 (256 thr): branch-free bf16x4 gather, 4 channels/thread. ----
__global__ __launch_bounds__(256) void sample_kernel(const float* __restrict__ oa,
                                                     const bf16_t* __restrict__ vp,
                                                     bf16_t* __restrict__ samp) {
    __shared__ float2 swo[4][8][17];   // [q][h][p*4+corner] = {weight, bits(index)}, padded
    int t = threadIdx.x;
    int q0 = blockIdx.x * 4;           // NQ%4==0 -> block never straddles batches
    if (t < 32) {
        int q = t >> 3, h = t & 7;
        int ng = q0 + q;
        int n = ng % NQ;
        const float* s = oa + (size_t)ng * 96;
        float l0 = s[64 + h * 4 + 0], l1 = s[64 + h * 4 + 1];
        float l2 = s[64 + h * 4 + 2], l3 = s[64 + h * 4 + 3];
        float mx = fmaxf(fmaxf(l0, l1), fmaxf(l2, l3));
        float e0 = expf(l0 - mx), e1 = expf(l1 - mx), e2 = expf(l2 - mx), e3 = expf(l3 - mx);
        float inv = 1.f / (e0 + e1 + e2 + e3);
        float aw[4] = {e0 * inv, e1 * inv, e2 * inv, e3 * inv};
        float xb = (float)(n % WW) * (80.f / 79.f) - 0.5f;
        float yb = (float)(n / WW) * (80.f / 79.f) - 0.5f;
#pragma unroll
        for (int p = 0; p < 4; p++) {
            float x = xb + s[h * 8 + p * 2];
            float y = yb + s[h * 8 + p * 2 + 1];
            float x0f = floorf(x), y0f = floorf(y);
            float wx = x - x0f, wy = y - y0f;
            int ix = (int)x0f, iy = (int)y0f;
            bool vx0 = (unsigned)ix < (unsigned)WW, vx1 = (unsigned)(ix + 1) < (unsigned)WW;
            bool vy0 = (unsigned)iy < (unsigned)HH, vy1 = (unsigned)(iy + 1) < (unsigned)HH;
            int cx0 = min(max(ix, 0), WW - 1), cx1 = min(max(ix + 1, 0), WW - 1);
            int cy0 = min(max(iy, 0), HH - 1), cy1 = min(max(iy + 1, 0), HH - 1);
            float ap = aw[p];
            float w00 = (vx0 && vy0) ? ap * (1.f - wx) * (1.f - wy) : 0.f;
            float w10 = (vx1 && vy0) ? ap * wx * (1.f - wy) : 0.f;
            float w01 = (vx0 && vy1) ? ap * (1.f - wx) * wy : 0.f;
            float w11 = (vx1 && vy1) ? ap * wx * wy : 0.f;
            swo[q][h][p * 4 + 0] = make_float2(w00, __int_as_float(cy0 * WW + cx0));
            swo[q][h][p * 4 + 1] = make_float2(w10, __int_as_float(cy0 * WW + cx1));
            swo[q][h][p * 4 + 2] = make_float2(w01, __int_as_float(cy1 * WW + cx0));
            swo[q][h][p * 4 + 3] = make_float2(w11, __int_as_float(cy1 * WW + cx1));
        }
    }
    __syncthreads();
    int q = t >> 6, h = (t >> 3) & 7, cg = t & 7;
    int ng = q0 + q;
    int b = ng / NQ;
    const bf16_t* vb = vp + (size_t)b * NQ * CD + h * 32 + cg * 4;
    f32x4 acc = {0.f, 0.f, 0.f, 0.f};
#pragma unroll
    for (int pc = 0; pc < 16; ++pc) {
        float2 wo = swo[q][h][pc];
        int off = __float_as_int(wo.y);
        bf16x4 v = *(const bf16x4*)(vb + (size_t)off * CD);
        acc[0] += (float)v[0] * wo.x;
        acc[1] += (float)v[1] * wo.x;
        acc[2] += (float)v[2] * wo.x;
        acc[3] += (float)v[3] * wo.x;
    }
    bf16x4 ov;
    ov[0] = (bf16_t)acc[0]; ov[1] = (bf16_t)acc[1];
    ov[2] = (bf16_t)acc[2]; ov[3] = (bf16_t)acc[3];
    *(bf16x4*)(samp + (size_t)ng * CD + h * 32 + cg * 4) = ov;
}

// ---- GEMM3: D[c'][n] = WoT[c'][:] . samp[n][:] ; vectorized LDS-transposed epilogue ----
__global__ __launch_bounds__(256, 2) void gemm_out(const bf16_t* __restrict__ X,   // WoT [256][256]
                                                   const bf16_t* __restrict__ Y,   // samp [51200][256]
                                                   const float* __restrict__ bout,
                                                   const float* __restrict__ query,
                                                   const float* __restrict__ value,
                                                   const float* __restrict__ pe,
                                                   float* __restrict__ out) {
    __shared__ __align__(16) char smem[32768];
    bf16_t* lx = (bf16_t*)smem;                 // 16 KB staging A
    bf16_t* ly = (bf16_t*)(smem + 16384);       // 16 KB staging B
    float* tile = (float*)smem;                 // epilogue overlay: [64][128] f32
    int m0 = blockIdx.y * 128;   // c'
    int n0 = blockIdx.x * 128;   // n_glob
    int tid = threadIdx.x, wv = tid >> 6, ln = tid & 63;
    f32x4 acc[4][4] = {};
    int wr = (wv >> 1) * 64, wc = (wv & 1) * 64;
    for (int kt = 0; kt < 4; ++kt) {
#pragma unroll
        for (int q8 = 0; q8 < 4; ++q8) {
            int q = wv * 4 + q8;
            int row = q * 8 + (ln >> 3);
            int jj = (ln & 7) ^ (row & 7);
            gload_lds16((const char*)X + ((size_t)(m0 + row)) * 512 + (size_t)kt * 128 + jj * 16,
                        (char*)lx + q * 1024);
            gload_lds16((const char*)Y + ((size_t)(n0 + row)) * 512 + (size_t)kt * 128 + jj * 16,
                        (char*)ly + q * 1024);
        }
        __syncthreads();
#pragma unroll
        for (int ks = 0; ks < 2; ++ks) {
            bf16x8 xa[4], yb[4];
#pragma unroll
            for (int i = 0; i < 4; i++) {
                int m = wr + i * 16 + (ln & 15);
                int ch = (ks * 4 + (ln >> 4)) ^ (m & 7);
                xa[i] = *(const bf16x8*)((const char*)lx + m * 128 + ch * 16);
                int n = wc + i * 16 + (ln & 15);
                int cn = (ks * 4 + (ln >> 4)) ^ (n & 7);
                yb[i] = *(const bf16x8*)((const char*)ly + n * 128 + cn * 16);
            }
#pragma unroll
            for (int i = 0; i < 4; i++)
#pragma unroll
                for (int j = 0; j < 4; j++)
                    acc[i][j] = __builtin_amdgcn_mfma_f32_16x16x32_bf16(xa[i], yb[j], acc[i][j], 0, 0, 0);
        }
        __syncthreads();
    }
    int b = n0 / NQ;
    int nb = n0 - b * NQ;
    const float* qp = query + (size_t)b * CD * NQ;
    const float* vp = value + (size_t)b * CD * NQ;
    float* o0 = out + (size_t)b * CD * NQ;
    float* o1 = out + OUT_HALF + (size_t)b * CD * NQ;
#pragma unroll
    for (int pass = 0; pass < 2; ++pass) {
        if ((wv >> 1) == pass) {
#pragma unroll
            for (int i = 0; i < 4; i++)
#pragma unroll
                for (int j = 0; j < 4; j++) {
                    int c = wc + j * 16 + (ln & 15);
#pragma unroll
                    for (int rg = 0; rg < 4; rg++) {
                        int r = i * 16 + (ln >> 4) * 4 + rg;
                        tile[r * 128 + c] = acc[i][j][rg] + bout[m0 + pass * 64 + r];
                    }
                }
        }
        __syncthreads();
        int g4 = (ln & 31) * 4;           // 4-float column group
        int rb = wv * 16 + (ln >> 5);     // base local row; +2 per iter
#pragma unroll
        for (int jj = 0; jj < 8; ++jj) {
            int r = rb + jj * 2;
            int crow = m0 + pass * 64 + r;
            size_t off = (size_t)crow * NQ + nb + g4;
            f32x4 tv = *(const f32x4*)&tile[r * 128 + g4];
            f32x4 qv = *(const f32x4*)(qp + off);
            f32x4 pv = *(const f32x4*)(pe + off);
            f32x4 vv = *(const f32x4*)(vp + off);
            f32x4 o1v = tv + qv + pv;
            *(f32x4*)(o1 + off) = o1v;
            *(f32x4*)(o0 + off) = o1v + vv;
        }
        __syncthreads();
    }
}

extern "C" void kernel_launch(void* const* d_in, const int* in_sizes, int n_in,
                              void* d_out, int out_size, void* d_ws, size_t ws_size,
                              hipStream_t stream) {
    const float* query   = (const float*)d_in[0];
    const float* value   = (const float*)d_in[1];
    const float* W_value = (const float*)d_in[2];
    const float* b_value = (const float*)d_in[3];
    const float* W_off   = (const float*)d_in[4];
    const float* b_off   = (const float*)d_in[5];
    const float* W_attn  = (const float*)d_in[6];
    const float* b_attn  = (const float*)d_in[7];
    const float* W_out   = (const float*)d_in[8];
    const float* b_out   = (const float*)d_in[9];
    float* out = (float*)d_out;
    char* ws = (char*)d_ws;

    float*  pe    = (float*)(ws + 0);              //  6,553,600
    bf16_t* vb16  = (bf16_t*)(ws + 6553600);       // 26,214,400 (dead after gemm_vproj)
    bf16_t* samp  = (bf16_t*)(ws + 6553600);       //   aliases vb16
    bf16_t* qb16  = (bf16_t*)(ws + 32768000);      // 26,214,400
    bf16_t* WvT   = (bf16_t*)(ws + 58982400);      //    131,072
    bf16_t* WoT   = (bf16_t*)(ws + 59113472);      //    131,072
    bf16_t* WoaT  = (bf16_t*)(ws + 59244544);      //     49,152
    bf16_t* vprojB= (bf16_t*)(ws + 59293696);      // 26,214,400
    float*  oa    = (float*)(ws + 85508096);       // 19,660,800  (total ~105.2 MB)

    pe_kernel<<<(CD * NQ + 255) / 256, 256, 0, stream>>>(pe);
    wprep_kernel<<<256, 256, 0, stream>>>(W_value, W_off, W_attn, W_out, WvT, WoaT, WoT);
    dim3 tb(32, 8);
    xpose_kernel<<<dim3(200, 8, BB), tb, 0, stream>>>(value, nullptr, vb16);
    xpose_kernel<<<dim3(200, 8, BB), tb, 0, stream>>>(query, pe, qb16);
    gemm_vproj<<<dim3(400, 2), 256, 0, stream>>>(vb16, WvT, b_value, vprojB);
    gemm_oa<<<dim3(400), 256, 0, stream>>>(qb16, WoaT, b_off, b_attn, oa);
    sample_kernel<<<BB * NQ / 4, 256, 0, stream>>>(oa, vprojB, samp);
    gemm_out<<<dim3(400, 2), 256, 0, stream>>>(WoT, samp, b_out, query, value, pe, out);
}

// Round 4
// 140.921 us; speedup vs baseline: 2.1049x; 1.0600x over previous
//
#include <hip/hip_runtime.h>
#include <hip/hip_bf16.h>
#include <stdint.h>

#define HH 80
#define WW 80
#define NQ 6400        // H*W
#define CD 256         // embed dim
#define BB 8
#define OUT_HALF 13107200   // B*C*H*W
#define PE_NEG 0.0719557841560639f   // ln(10000)/128

typedef __attribute__((ext_vector_type(4))) float f32x4;
typedef __bf16 bf16_t;
typedef __attribute__((ext_vector_type(8))) __bf16 bf16x8;
typedef __attribute__((ext_vector_type(4))) __bf16 bf16x4;
typedef _Float16 f16_t;

using gp1_t = const __attribute__((address_space(1))) void*;
using lp3_t = __attribute__((address_space(3))) void*;

__device__ __forceinline__ void gload_lds16(const void* g, void* l) {
    __builtin_amdgcn_global_load_lds((gp1_t)g, (lp3_t)l, 16, 0, 0);
}

// ---------------- PE table: pe[c][n], f32 (consumed by gemm_out epilogue) ----------------
__global__ __launch_bounds__(256) void pe_kernel(float* __restrict__ pe) {
    int idx = blockIdx.x * 256 + threadIdx.x;
    if (idx >= CD * NQ) return;
    int c = idx / NQ, n = idx % NQ;
    int h = n / WW, w = n % WW;
    int k = c >> 2;
    float d = expf((float)(2 * k) * -PE_NEG);
    float arg = ((c & 2) ? (float)(h + 1) : (float)(w + 1)) * d;
    pe[idx] = (c & 1) ? cosf(arg) : sinf(arg);
}

// ---------------- weight transposes -> bf16, rows = output col, K-contig ----------------
__global__ __launch_bounds__(256) void wprep_kernel(const float* __restrict__ Wv,
                                                    const float* __restrict__ Woff,
                                                    const float* __restrict__ Wattn,
                                                    const float* __restrict__ Wout,
                                                    bf16_t* __restrict__ WvT,
                                                    bf16_t* __restrict__ WoaT,
                                                    bf16_t* __restrict__ WoT) {
    int idx = blockIdx.x * 256 + threadIdx.x;
    if (idx < 65536) {
        int cp = idx >> 8, c = idx & 255;
        WvT[idx] = (bf16_t)Wv[c * 256 + cp];
        WoT[idx] = (bf16_t)Wout[c * 256 + cp];
    }
    if (idx < 96 * 256) {
        int j = idx >> 8, c = idx & 255;
        WoaT[idx] = (bf16_t)(j < 64 ? Woff[c * 64 + j] : Wattn[c * 32 + (j - 64)]);
    }
}

// ================= GEMM cores =================
// B-operand (weights): LDS rows of 128 B (8×16B chunks), XOR-swizzled chunk^(row&7),
//   staged via gload_lds with inverse-swizzled global source.
// A-operand (activations, [c][n] f32 in memory): reg-staged LDS transpose into
//   [n][k] bf16 tile with row stride 144 B (aligned b128 frags; reads 2-way=free).

// ---- GEMM1: vproj[n][c'] = (value^T)[n][:] . WvT[c'][:] + b_value[c']  (bf16 out) ----
__global__ __launch_bounds__(256, 2) void gemm_vproj(const float* __restrict__ V,   // [b][c][n] f32
                                                     const bf16_t* __restrict__ Y,  // WvT [c'][c]
                                                     const float* __restrict__ bias,
                                                     bf16_t* __restrict__ D) {
    __shared__ __align__(16) bf16_t lx[128 * 72];   // [n][k] stride 72 elems = 144 B
    __shared__ __align__(16) bf16_t ly[128 * 64];
    int m0 = blockIdx.x * 128;        // global n rows (across batches; 50 blocks/batch)
    int c0 = blockIdx.y * 128;        // c' tile
    int b = m0 / NQ, nloc = m0 % NQ;
    const float* src = V + (size_t)b * CD * NQ + nloc;
    int tid = threadIdx.x, wv = tid >> 6, ln = tid & 63;
    f32x4 acc[4][4] = {};
    int wr = (wv >> 1) * 64, wc = (wv & 1) * 64;
    int nl = tid & 31;
    for (int kt = 0; kt < 4; ++kt) {
        // B stage
#pragma unroll
        for (int q8 = 0; q8 < 4; ++q8) {
            int q = wv * 4 + q8;
            int row = q * 8 + (ln >> 3);
            int jj = (ln & 7) ^ (row & 7);
            gload_lds16((const char*)Y + ((size_t)(c0 + row)) * 512 + (size_t)kt * 128 + jj * 16,
                        (char*)ly + q * 1024);
        }
        // A stage: k-pair transpose
#pragma unroll
        for (int i = 0; i < 4; ++i) {
            int kp = (tid >> 5) + i * 8;          // 0..31
            int k = kp * 2;
            const float* s0 = src + (size_t)(kt * 64 + k) * NQ;
#pragma unroll
            for (int l = 0; l < 4; ++l) {
                int n = nl + 32 * l;
                float v0 = s0[n];
                float v1 = s0[NQ + n];
                union { bf16_t h[2]; uint32_t u; } pk;
                pk.h[0] = (bf16_t)v0; pk.h[1] = (bf16_t)v1;
                *(uint32_t*)((char*)lx + n * 144 + k * 2) = pk.u;
            }
        }
        __syncthreads();
#pragma unroll
        for (int ks = 0; ks < 2; ++ks) {
            bf16x8 xa[4], yb[4];
#pragma unroll
            for (int i = 0; i < 4; i++) {
                int m = wr + i * 16 + (ln & 15);
                xa[i] = *(const bf16x8*)((const char*)lx + m * 144 + ks * 64 + (ln >> 4) * 16);
                int n = wc + i * 16 + (ln & 15);
                int cn = (ks * 4 + (ln >> 4)) ^ (n & 7);
                yb[i] = *(const bf16x8*)((const char*)ly + n * 128 + cn * 16);
            }
#pragma unroll
            for (int i = 0; i < 4; i++)
#pragma unroll
                for (int j = 0; j < 4; j++)
                    acc[i][j] = __builtin_amdgcn_mfma_f32_16x16x32_bf16(xa[i], yb[j], acc[i][j], 0, 0, 0);
        }
        __syncthreads();
    }
#pragma unroll
    for (int i = 0; i < 4; i++)
#pragma unroll
        for (int j = 0; j < 4; j++) {
            int col = c0 + wc + j * 16 + (ln & 15);
            float bv = bias[col];
#pragma unroll
            for (int rg = 0; rg < 4; rg++) {
                int row = m0 + wr + i * 16 + (ln >> 4) * 4 + rg;
                D[(size_t)row * 256 + col] = (bf16_t)(acc[i][j][rg] + bv);
            }
        }
}

// ---- GEMM2: oa[n][j] = (query+PE)^T[n][:] . WoaT[j][:] + bias_j  (f16 out, N=96) ----
__global__ __launch_bounds__(256, 2) void gemm_oa(const float* __restrict__ Q,    // [b][c][n] f32
                                                  const bf16_t* __restrict__ Y,   // WoaT [j][c]
                                                  const float* __restrict__ boff,
                                                  const float* __restrict__ battn,
                                                  f16_t* __restrict__ D) {
    __shared__ __align__(16) bf16_t lx[128 * 72];
    __shared__ __align__(16) bf16_t ly[96 * 64];
    int m0 = blockIdx.x * 128;
    int b = m0 / NQ, nloc = m0 % NQ;
    const float* src = Q + (size_t)b * CD * NQ + nloc;
    int tid = threadIdx.x, wv = tid >> 6, ln = tid & 63;
    f32x4 acc[2][6] = {};
    int nl = tid & 31;
    for (int kt = 0; kt < 4; ++kt) {
#pragma unroll
        for (int q3 = 0; q3 < 3; ++q3) {
            int q = wv * 3 + q3;
            int row = q * 8 + (ln >> 3);
            int jj = (ln & 7) ^ (row & 7);
            gload_lds16((const char*)Y + ((size_t)row) * 512 + (size_t)kt * 128 + jj * 16,
                        (char*)ly + q * 1024);
        }
        // A stage with inline PE: rows c0k (even -> sin) and c0k+1 (odd -> cos) share arg
#pragma unroll
        for (int i = 0; i < 4; ++i) {
            int kp = (tid >> 5) + i * 8;
            int k = kp * 2;
            int c = kt * 64 + k;
            float d = expf((float)(2 * (c >> 2)) * -PE_NEG);
            const float* s0 = src + (size_t)c * NQ;
#pragma unroll
            for (int l = 0; l < 4; ++l) {
                int n = nl + 32 * l;
                int p = nloc + n;
                int h = p / WW, w = p - h * WW;
                float pos = (c & 2) ? (float)(h + 1) : (float)(w + 1);
                float sv, cv;
                sincosf(pos * d, &sv, &cv);
                float v0 = s0[n] + sv;
                float v1 = s0[NQ + n] + cv;
                union { bf16_t hh[2]; uint32_t u; } pk;
                pk.hh[0] = (bf16_t)v0; pk.hh[1] = (bf16_t)v1;
                *(uint32_t*)((char*)lx + n * 144 + k * 2) = pk.u;
            }
        }
        __syncthreads();
#pragma unroll
        for (int ks = 0; ks < 2; ++ks) {
            bf16x8 xa[2], yb[6];
#pragma unroll
            for (int i = 0; i < 2; i++) {
                int m = wv * 32 + i * 16 + (ln & 15);
                xa[i] = *(const bf16x8*)((const char*)lx + m * 144 + ks * 64 + (ln >> 4) * 16);
            }
#pragma unroll
            for (int j = 0; j < 6; j++) {
                int n = j * 16 + (ln & 15);
                int cn = (ks * 4 + (ln >> 4)) ^ (n & 7);
                yb[j] = *(const bf16x8*)((const char*)ly + n * 128 + cn * 16);
            }
#pragma unroll
            for (int i = 0; i < 2; i++)
#pragma unroll
                for (int j = 0; j < 6; j++)
                    acc[i][j] = __builtin_amdgcn_mfma_f32_16x16x32_bf16(xa[i], yb[j], acc[i][j], 0, 0, 0);
        }
        __syncthreads();
    }
#pragma unroll
    for (int i = 0; i < 2; i++)
#pragma unroll
        for (int j = 0; j < 6; j++) {
            int col = j * 16 + (ln & 15);
            float bv = col < 64 ? boff[col] : battn[col - 64];
#pragma unroll
            for (int rg = 0; rg < 4; rg++) {
                int row = m0 + wv * 32 + i * 16 + (ln >> 4) * 4 + rg;
                D[(size_t)row * 96 + col] = (f16_t)(acc[i][j][rg] + bv);
            }
        }
}

// ---- sampling: 4 queries/block, XCD-swizzled so each XCD owns one batch (vproj slice
//      fits 4MB L2). Phase1 (32 thr): softmax+weights+indices per (q,h) into LDS.
//      Phase2 (256 thr): branch-free bf16x4 gather, 4 channels/thread. ----
__global__ __launch_bounds__(256) void sample_kernel(const f16_t* __restrict__ oa,
                                                     const bf16_t* __restrict__ vp,
                                                     bf16_t* __restrict__ samp) {
    __shared__ float2 swo[4][8][17];
    __shared__ float s[4][96];
    int t = threadIdx.x;
    int bid = blockIdx.x;                       // 12800 blocks, %8==0
    int q0 = (((bid & 7) * 1600) + (bid >> 3)) * 4;
    // load 4*96 f16 -> f32 LDS
    if (t < 192) {
        int q = t / 48, e = (t % 48) * 2;
        const f16_t* sp = oa + (size_t)(q0 + q) * 96 + e;
        s[q][e] = (float)sp[0];
        s[q][e + 1] = (float)sp[1];
    }
    __syncthreads();
    if (t < 32) {
        int q = t >> 3, h = t & 7;
        int ng = q0 + q;
        int n = ng % NQ;
        const float* sq = s[q];
        float l0 = sq[64 + h * 4 + 0], l1 = sq[64 + h * 4 + 1];
        float l2 = sq[64 + h * 4 + 2], l3 = sq[64 + h * 4 + 3];
        float mx = fmaxf(fmaxf(l0, l1), fmaxf(l2, l3));
        float e0 = expf(l0 - mx), e1 = expf(l1 - mx), e2 = expf(l2 - mx), e3 = expf(l3 - mx);
        float inv = 1.f / (e0 + e1 + e2 + e3);
        float aw[4] = {e0 * inv, e1 * inv, e2 * inv, e3 * inv};
        float xb = (float)(n % WW) * (80.f / 79.f) - 0.5f;
        float yb = (float)(n / WW) * (80.f / 79.f) - 0.5f;
#pragma unroll
        for (int p = 0; p < 4; p++) {
            float x = xb + sq[h * 8 + p * 2];
            float y = yb + sq[h * 8 + p * 2 + 1];
            float x0f = floorf(x), y0f = floorf(y);
            float wx = x - x0f, wy = y - y0f;
            int ix = (int)x0f, iy = (int)y0f;
            bool vx0 = (unsigned)ix < (unsigned)WW, vx1 = (unsigned)(ix + 1) < (unsigned)WW;
            bool vy0 = (unsigned)iy < (unsigned)HH, vy1 = (unsigned)(iy + 1) < (unsigned)HH;
            int cx0 = min(max(ix, 0), WW - 1), cx1 = min(max(ix + 1, 0), WW - 1);
            int cy0 = min(max(iy, 0), HH - 1), cy1 = min(max(iy + 1, 0), HH - 1);
            float ap = aw[p];
            float w00 = (vx0 && vy0) ? ap * (1.f - wx) * (1.f - wy) : 0.f;
            float w10 = (vx1 && vy0) ? ap * wx * (1.f - wy) : 0.f;
            float w01 = (vx0 && vy1) ? ap * (1.f - wx) * wy : 0.f;
            float w11 = (vx1 && vy1) ? ap * wx * wy : 0.f;
            swo[q][h][p * 4 + 0] = make_float2(w00, __int_as_float(cy0 * WW + cx0));
            swo[q][h][p * 4 + 1] = make_float2(w10, __int_as_float(cy0 * WW + cx1));
            swo[q][h][p * 4 + 2] = make_float2(w01, __int_as_float(cy1 * WW + cx0));
            swo[q][h][p * 4 + 3] = make_float2(w11, __int_as_float(cy1 * WW + cx1));
        }
    }
    __syncthreads();
    int q = t >> 6, h = (t >> 3) & 7, cg = t & 7;
    int ng = q0 + q;
    int b = ng / NQ;
    const bf16_t* vb = vp + (size_t)b * NQ * CD + h * 32 + cg * 4;
    f32x4 acc = {0.f, 0.f, 0.f, 0.f};
#pragma unroll
    for (int pc = 0; pc < 16; ++pc) {
        float2 wo = swo[q][h][pc];
        int off = __float_as_int(wo.y);
        bf16x4 v = *(const bf16x4*)(vb + (size_t)off * CD);
        acc[0] += (float)v[0] * wo.x;
        acc[1] += (float)v[1] * wo.x;
        acc[2] += (float)v[2] * wo.x;
        acc[3] += (float)v[3] * wo.x;
    }
    bf16x4 ov;
    ov[0] = (bf16_t)acc[0]; ov[1] = (bf16_t)acc[1];
    ov[2] = (bf16_t)acc[2]; ov[3] = (bf16_t)acc[3];
    *(bf16x4*)(samp + (size_t)ng * CD + h * 32 + cg * 4) = ov;
}

// ---- GEMM3: D[c'][n] = WoT[c'][:] . samp[n][:] ; vectorized LDS-transposed epilogue ----
__global__ __launch_bounds__(256, 2) void gemm_out(const bf16_t* __restrict__ X,   // WoT [256][256]
                                                   const bf16_t* __restrict__ Y,   // samp [51200][256]
                                                   const float* __restrict__ bout,
                                                   const float* __restrict__ query,
                                                   const float* __restrict__ value,
                                                   const float* __restrict__ pe,
                                                   float* __restrict__ out) {
    __shared__ __align__(16) char smem[32768];
    bf16_t* lx = (bf16_t*)smem;
    bf16_t* ly = (bf16_t*)(smem + 16384);
    float* tile = (float*)smem;                 // epilogue overlay: [64][128] f32
    int m0 = blockIdx.y * 128;   // c'
    int n0 = blockIdx.x * 128;   // n_glob
    int tid = threadIdx.x, wv = tid >> 6, ln = tid & 63;
    f32x4 acc[4][4] = {};
    int wr = (wv >> 1) * 64, wc = (wv & 1) * 64;
    for (int kt = 0; kt < 4; ++kt) {
#pragma unroll
        for (int q8 = 0; q8 < 4; ++q8) {
            int q = wv * 4 + q8;
            int row = q * 8 + (ln >> 3);
            int jj = (ln & 7) ^ (row & 7);
            gload_lds16((const char*)X + ((size_t)(m0 + row)) * 512 + (size_t)kt * 128 + jj * 16,
                        (char*)lx + q * 1024);
            gload_lds16((const char*)Y + ((size_t)(n0 + row)) * 512 + (size_t)kt * 128 + jj * 16,
                        (char*)ly + q * 1024);
        }
        __syncthreads();
#pragma unroll
        for (int ks = 0; ks < 2; ++ks) {
            bf16x8 xa[4], yb[4];
#pragma unroll
            for (int i = 0; i < 4; i++) {
                int m = wr + i * 16 + (ln & 15);
                int ch = (ks * 4 + (ln >> 4)) ^ (m & 7);
                xa[i] = *(const bf16x8*)((const char*)lx + m * 128 + ch * 16);
                int n = wc + i * 16 + (ln & 15);
                int cn = (ks * 4 + (ln >> 4)) ^ (n & 7);
                yb[i] = *(const bf16x8*)((const char*)ly + n * 128 + cn * 16);
            }
#pragma unroll
            for (int i = 0; i < 4; i++)
#pragma unroll
                for (int j = 0; j < 4; j++)
                    acc[i][j] = __builtin_amdgcn_mfma_f32_16x16x32_bf16(xa[i], yb[j], acc[i][j], 0, 0, 0);
        }
        __syncthreads();
    }
    int b = n0 / NQ;
    int nb = n0 - b * NQ;
    const float* qp = query + (size_t)b * CD * NQ;
    const float* vp = value + (size_t)b * CD * NQ;
    float* o0 = out + (size_t)b * CD * NQ;
    float* o1 = out + OUT_HALF + (size_t)b * CD * NQ;
#pragma unroll
    for (int pass = 0; pass < 2; ++pass) {
        if ((wv >> 1) == pass) {
#pragma unroll
            for (int i = 0; i < 4; i++)
#pragma unroll
                for (int j = 0; j < 4; j++) {
                    int c = wc + j * 16 + (ln & 15);
#pragma unroll
                    for (int rg = 0; rg < 4; rg++) {
                        int r = i * 16 + (ln >> 4) * 4 + rg;
                        tile[r * 128 + c] = acc[i][j][rg] + bout[m0 + pass * 64 + r];
                    }
                }
        }
        __syncthreads();
        int g4 = (ln & 31) * 4;
        int rb = wv * 16 + (ln >> 5);
#pragma unroll
        for (int jj = 0; jj < 8; ++jj) {
            int r = rb + jj * 2;
            int crow = m0 + pass * 64 + r;
            size_t off = (size_t)crow * NQ + nb + g4;
            f32x4 tv = *(const f32x4*)&tile[r * 128 + g4];
            f32x4 qv = *(const f32x4*)(qp + off);
            f32x4 pv = *(const f32x4*)(pe + off);
            f32x4 vv = *(const f32x4*)(vp + off);
            f32x4 o1v = tv + qv + pv;
            *(f32x4*)(o1 + off) = o1v;
            *(f32x4*)(o0 + off) = o1v + vv;
        }
        __syncthreads();
    }
}

extern "C" void kernel_launch(void* const* d_in, const int* in_sizes, int n_in,
                              void* d_out, int out_size, void* d_ws, size_t ws_size,
                              hipStream_t stream) {
    const float* query   = (const float*)d_in[0];
    const float* value   = (const float*)d_in[1];
    const float* W_value = (const float*)d_in[2];
    const float* b_value = (const float*)d_in[3];
    const float* W_off   = (const float*)d_in[4];
    const float* b_off   = (const float*)d_in[5];
    const float* W_attn  = (const float*)d_in[6];
    const float* b_attn  = (const float*)d_in[7];
    const float* W_out   = (const float*)d_in[8];
    const float* b_out   = (const float*)d_in[9];
    float* out = (float*)d_out;
    char* ws = (char*)d_ws;

    float*  pe    = (float*)(ws + 0);              //  6,553,600
    bf16_t* WvT   = (bf16_t*)(ws + 6553600);       //    131,072
    bf16_t* WoT   = (bf16_t*)(ws + 6684672);       //    131,072
    bf16_t* WoaT  = (bf16_t*)(ws + 6815744);       //     49,152
    bf16_t* vprojB= (bf16_t*)(ws + 6864896);       // 26,214,400
    f16_t*  oaH   = (f16_t*)(ws + 33079296);       //  9,830,400
    bf16_t* samp  = (bf16_t*)(ws + 42909696);      // 26,214,400  (total ~69.1 MB)

    pe_kernel<<<(CD * NQ + 255) / 256, 256, 0, stream>>>(pe);
    wprep_kernel<<<256, 256, 0, stream>>>(W_value, W_off, W_attn, W_out, WvT, WoaT, WoT);
    gemm_vproj<<<dim3(400, 2), 256, 0, stream>>>(value, WvT, b_value, vprojB);
    gemm_oa<<<dim3(400), 256, 0, stream>>>(query, WoaT, b_off, b_attn, oaH);
    sample_kernel<<<BB * NQ / 4, 256, 0, stream>>>(oaH, vprojB, samp);
    gemm_out<<<dim3(400, 2), 256, 0, stream>>>(WoT, samp, b_out, query, value, pe, out);
}

// Round 5
// 137.190 us; speedup vs baseline: 2.1622x; 1.0272x over previous
//
#include <hip/hip_runtime.h>
#include <hip/hip_bf16.h>
#include <stdint.h>

#define HH 80
#define WW 80
#define NQ 6400        // H*W
#define CD 256         // embed dim
#define BB 8
#define OUT_HALF 13107200   // B*C*H*W
#define PE_NEG 0.0719557841560639f   // ln(10000)/128

typedef __attribute__((ext_vector_type(4))) float f32x4;
typedef __bf16 bf16_t;
typedef __attribute__((ext_vector_type(8))) __bf16 bf16x8;
typedef __attribute__((ext_vector_type(4))) __bf16 bf16x4;
typedef _Float16 f16_t;
typedef __attribute__((ext_vector_type(8))) _Float16 f16x8;

using gp1_t = const __attribute__((address_space(1))) void*;
using lp3_t = __attribute__((address_space(3))) void*;

__device__ __forceinline__ void gload_lds16(const void* g, void* l) {
    __builtin_amdgcn_global_load_lds((gp1_t)g, (lp3_t)l, 16, 0, 0);
}

// ---------------- PE table: pe[c][n], f32 (consumed by gemm_out epilogue) ----------------
__global__ __launch_bounds__(256) void pe_kernel(float* __restrict__ pe) {
    int idx = blockIdx.x * 256 + threadIdx.x;
    if (idx >= CD * NQ) return;
    int c = idx / NQ, n = idx % NQ;
    int h = n / WW, w = n % WW;
    int k = c >> 2;
    float d = expf((float)(2 * k) * -PE_NEG);
    float arg = ((c & 2) ? (float)(h + 1) : (float)(w + 1)) * d;
    pe[idx] = (c & 1) ? cosf(arg) : sinf(arg);
}

// ---------------- weight transposes -> bf16, rows = output col, K-contig ----------------
__global__ __launch_bounds__(256) void wprep_kernel(const float* __restrict__ Wv,
                                                    const float* __restrict__ Woff,
                                                    const float* __restrict__ Wattn,
                                                    const float* __restrict__ Wout,
                                                    bf16_t* __restrict__ WvT,
                                                    bf16_t* __restrict__ WoaT,
                                                    bf16_t* __restrict__ WoT) {
    int idx = blockIdx.x * 256 + threadIdx.x;
    if (idx < 65536) {
        int cp = idx >> 8, c = idx & 255;
        WvT[idx] = (bf16_t)Wv[c * 256 + cp];
        WoT[idx] = (bf16_t)Wout[c * 256 + cp];
    }
    if (idx < 96 * 256) {
        int j = idx >> 8, c = idx & 255;
        WoaT[idx] = (bf16_t)(j < 64 ? Woff[c * 64 + j] : Wattn[c * 32 + (j - 64)]);
    }
}

// ================= GEMM cores =================
// B-operand (weights): LDS rows of 128 B (8×16B chunks), XOR-swizzled chunk^(row&7),
//   staged via gload_lds with inverse-swizzled global source.
// A-operand (activations, [c][n] f32 in memory): reg-staged LDS transpose into
//   [n][k] bf16 tile with row stride 144 B (aligned b128 frags; reads 2-way=free).

// ---- GEMM1: vproj[n][c'] = (value^T)[n][:] . WvT[c'][:] + b_value[c']  (bf16 out) ----
__global__ __launch_bounds__(256, 2) void gemm_vproj(const float* __restrict__ V,   // [b][c][n] f32
                                                     const bf16_t* __restrict__ Y,  // WvT [c'][c]
                                                     const float* __restrict__ bias,
                                                     bf16_t* __restrict__ D) {
    __shared__ __align__(16) bf16_t lx[128 * 72];   // [n][k] stride 72 elems = 144 B
    __shared__ __align__(16) bf16_t ly[128 * 64];
    int m0 = blockIdx.x * 128;        // global n rows (across batches; 50 blocks/batch)
    int c0 = blockIdx.y * 128;        // c' tile
    int b = m0 / NQ, nloc = m0 % NQ;
    const float* src = V + (size_t)b * CD * NQ + nloc;
    int tid = threadIdx.x, wv = tid >> 6, ln = tid & 63;
    f32x4 acc[4][4] = {};
    int wr = (wv >> 1) * 64, wc = (wv & 1) * 64;
    int nl = tid & 31;
    for (int kt = 0; kt < 4; ++kt) {
        // B stage
#pragma unroll
        for (int q8 = 0; q8 < 4; ++q8) {
            int q = wv * 4 + q8;
            int row = q * 8 + (ln >> 3);
            int jj = (ln & 7) ^ (row & 7);
            gload_lds16((const char*)Y + ((size_t)(c0 + row)) * 512 + (size_t)kt * 128 + jj * 16,
                        (char*)ly + q * 1024);
        }
        // A stage: k-pair transpose
#pragma unroll
        for (int i = 0; i < 4; ++i) {
            int kp = (tid >> 5) + i * 8;          // 0..31
            int k = kp * 2;
            const float* s0 = src + (size_t)(kt * 64 + k) * NQ;
#pragma unroll
            for (int l = 0; l < 4; ++l) {
                int n = nl + 32 * l;
                float v0 = s0[n];
                float v1 = s0[NQ + n];
                union { bf16_t h[2]; uint32_t u; } pk;
                pk.h[0] = (bf16_t)v0; pk.h[1] = (bf16_t)v1;
                *(uint32_t*)((char*)lx + n * 144 + k * 2) = pk.u;
            }
        }
        __syncthreads();
#pragma unroll
        for (int ks = 0; ks < 2; ++ks) {
            bf16x8 xa[4], yb[4];
#pragma unroll
            for (int i = 0; i < 4; i++) {
                int m = wr + i * 16 + (ln & 15);
                xa[i] = *(const bf16x8*)((const char*)lx + m * 144 + ks * 64 + (ln >> 4) * 16);
                int n = wc + i * 16 + (ln & 15);
                int cn = (ks * 4 + (ln >> 4)) ^ (n & 7);
                yb[i] = *(const bf16x8*)((const char*)ly + n * 128 + cn * 16);
            }
#pragma unroll
            for (int i = 0; i < 4; i++)
#pragma unroll
                for (int j = 0; j < 4; j++)
                    acc[i][j] = __builtin_amdgcn_mfma_f32_16x16x32_bf16(xa[i], yb[j], acc[i][j], 0, 0, 0);
        }
        __syncthreads();
    }
#pragma unroll
    for (int i = 0; i < 4; i++)
#pragma unroll
        for (int j = 0; j < 4; j++) {
            int col = c0 + wc + j * 16 + (ln & 15);
            float bv = bias[col];
#pragma unroll
            for (int rg = 0; rg < 4; rg++) {
                int row = m0 + wr + i * 16 + (ln >> 4) * 4 + rg;
                D[(size_t)row * 256 + col] = (bf16_t)(acc[i][j][rg] + bv);
            }
        }
}

// ---- GEMM2: oa[n][j] = (query+PE)^T[n][:] . WoaT[j][:] + bias_j  (f16 out, N=96) ----
__global__ __launch_bounds__(256, 2) void gemm_oa(const float* __restrict__ Q,    // [b][c][n] f32
                                                  const bf16_t* __restrict__ Y,   // WoaT [j][c]
                                                  const float* __restrict__ boff,
                                                  const float* __restrict__ battn,
                                                  f16_t* __restrict__ D) {
    __shared__ __align__(16) bf16_t lx[128 * 72];
    __shared__ __align__(16) bf16_t ly[96 * 64];
    int m0 = blockIdx.x * 128;
    int b = m0 / NQ, nloc = m0 % NQ;
    const float* src = Q + (size_t)b * CD * NQ + nloc;
    int tid = threadIdx.x, wv = tid >> 6, ln = tid & 63;
    f32x4 acc[2][6] = {};
    int nl = tid & 31;
    for (int kt = 0; kt < 4; ++kt) {
#pragma unroll
        for (int q3 = 0; q3 < 3; ++q3) {
            int q = wv * 3 + q3;
            int row = q * 8 + (ln >> 3);
            int jj = (ln & 7) ^ (row & 7);
            gload_lds16((const char*)Y + ((size_t)row) * 512 + (size_t)kt * 128 + jj * 16,
                        (char*)ly + q * 1024);
        }
        // A stage with inline PE: rows c0k (even -> sin) and c0k+1 (odd -> cos) share arg
#pragma unroll
        for (int i = 0; i < 4; ++i) {
            int kp = (tid >> 5) + i * 8;
            int k = kp * 2;
            int c = kt * 64 + k;
            float d = expf((float)(2 * (c >> 2)) * -PE_NEG);
            const float* s0 = src + (size_t)c * NQ;
#pragma unroll
            for (int l = 0; l < 4; ++l) {
                int n = nl + 32 * l;
                int p = nloc + n;
                int h = p / WW, w = p - h * WW;
                float pos = (c & 2) ? (float)(h + 1) : (float)(w + 1);
                float sv, cv;
                sincosf(pos * d, &sv, &cv);
                float v0 = s0[n] + sv;
                float v1 = s0[NQ + n] + cv;
                union { bf16_t hh[2]; uint32_t u; } pk;
                pk.hh[0] = (bf16_t)v0; pk.hh[1] = (bf16_t)v1;
                *(uint32_t*)((char*)lx + n * 144 + k * 2) = pk.u;
            }
        }
        __syncthreads();
#pragma unroll
        for (int ks = 0; ks < 2; ++ks) {
            bf16x8 xa[2], yb[6];
#pragma unroll
            for (int i = 0; i < 2; i++) {
                int m = wv * 32 + i * 16 + (ln & 15);
                xa[i] = *(const bf16x8*)((const char*)lx + m * 144 + ks * 64 + (ln >> 4) * 16);
            }
#pragma unroll
            for (int j = 0; j < 6; j++) {
                int n = j * 16 + (ln & 15);
                int cn = (ks * 4 + (ln >> 4)) ^ (n & 7);
                yb[j] = *(const bf16x8*)((const char*)ly + n * 128 + cn * 16);
            }
#pragma unroll
            for (int i = 0; i < 2; i++)
#pragma unroll
                for (int j = 0; j < 6; j++)
                    acc[i][j] = __builtin_amdgcn_mfma_f32_16x16x32_bf16(xa[i], yb[j], acc[i][j], 0, 0, 0);
        }
        __syncthreads();
    }
#pragma unroll
    for (int i = 0; i < 2; i++)
#pragma unroll
        for (int j = 0; j < 6; j++) {
            int col = j * 16 + (ln & 15);
            float bv = col < 64 ? boff[col] : battn[col - 64];
#pragma unroll
            for (int rg = 0; rg < 4; rg++) {
                int row = m0 + wv * 32 + i * 16 + (ln >> 4) * 4 + rg;
                D[(size_t)row * 96 + col] = (f16_t)(acc[i][j][rg] + bv);
            }
        }
}

// ---- sampling v3: 16 queries/block (grid 3200), XCD-swizzled (batch = bid&7).
//      Phase0: oa f16x8 loads -> LDS. Phase1: 128 thr, one (q,h) each: softmax+16 (w,idx).
//      Phase2: 256 thr = (q,h,half): 16 corners x 2 bf16x8 gathers, 16 f32 acc. ----
__global__ __launch_bounds__(256) void sample_kernel(const f16_t* __restrict__ oa,
                                                     const bf16_t* __restrict__ vp,
                                                     bf16_t* __restrict__ samp) {
    __shared__ float s[16][100];          // padded: bank = 4q + f(h)
    __shared__ float2 swo[16][8][17];     // [q][h][p*4+corner], padded
    int t = threadIdx.x;
    int bid = blockIdx.x;                 // 3200 = 8 batches * 400
    int b = bid & 7;
    int nq0 = (bid >> 3) * 16;            // local query base within batch
    size_t q0g = (size_t)b * NQ + nq0;    // global query base
    // phase 0: load 16x96 f16 -> f32 LDS
    if (t < 192) {
        int q = t / 12, e = (t % 12) * 8;
        f16x8 v = *(const f16x8*)(oa + (q0g + q) * 96 + e);
#pragma unroll
        for (int j = 0; j < 8; j++) s[q][e + j] = (float)v[j];
    }
    __syncthreads();
    // phase 1: one (q,h) per thread, t < 128
    if (t < 128) {
        int q = t >> 3, h = t & 7;
        int n = nq0 + q;
        const float* sq = s[q];
        float l0 = sq[64 + h * 4 + 0], l1 = sq[64 + h * 4 + 1];
        float l2 = sq[64 + h * 4 + 2], l3 = sq[64 + h * 4 + 3];
        float mx = fmaxf(fmaxf(l0, l1), fmaxf(l2, l3));
        float e0 = expf(l0 - mx), e1 = expf(l1 - mx), e2 = expf(l2 - mx), e3 = expf(l3 - mx);
        float inv = 1.f / (e0 + e1 + e2 + e3);
        float aw[4] = {e0 * inv, e1 * inv, e2 * inv, e3 * inv};
        float xb = (float)(n % WW) * (80.f / 79.f) - 0.5f;
        float yb = (float)(n / WW) * (80.f / 79.f) - 0.5f;
#pragma unroll
        for (int p = 0; p < 4; p++) {
            float x = xb + sq[h * 8 + p * 2];
            float y = yb + sq[h * 8 + p * 2 + 1];
            float x0f = floorf(x), y0f = floorf(y);
            float wx = x - x0f, wy = y - y0f;
            int ix = (int)x0f, iy = (int)y0f;
            bool vx0 = (unsigned)ix < (unsigned)WW, vx1 = (unsigned)(ix + 1) < (unsigned)WW;
            bool vy0 = (unsigned)iy < (unsigned)HH, vy1 = (unsigned)(iy + 1) < (unsigned)HH;
            int cx0 = min(max(ix, 0), WW - 1), cx1 = min(max(ix + 1, 0), WW - 1);
            int cy0 = min(max(iy, 0), HH - 1), cy1 = min(max(iy + 1, 0), HH - 1);
            float ap = aw[p];
            float w00 = (vx0 && vy0) ? ap * (1.f - wx) * (1.f - wy) : 0.f;
            float w10 = (vx1 && vy0) ? ap * wx * (1.f - wy) : 0.f;
            float w01 = (vx0 && vy1) ? ap * (1.f - wx) * wy : 0.f;
            float w11 = (vx1 && vy1) ? ap * wx * wy : 0.f;
            swo[q][h][p * 4 + 0] = make_float2(w00, __int_as_float(cy0 * WW + cx0));
            swo[q][h][p * 4 + 1] = make_float2(w10, __int_as_float(cy0 * WW + cx1));
            swo[q][h][p * 4 + 2] = make_float2(w01, __int_as_float(cy1 * WW + cx0));
            swo[q][h][p * 4 + 3] = make_float2(w11, __int_as_float(cy1 * WW + cx1));
        }
    }
    __syncthreads();
    // phase 2: (q, h, half): 16 channels each
    int q = t >> 4, h = (t >> 1) & 7, sh = t & 1;
    const bf16_t* vb = vp + (size_t)b * NQ * CD + h * 32 + sh * 16;
    float acc[16];
#pragma unroll
    for (int j = 0; j < 16; j++) acc[j] = 0.f;
#pragma unroll
    for (int pc = 0; pc < 16; ++pc) {
        float2 wo = swo[q][h][pc];
        int off = __float_as_int(wo.y);
        const bf16x8* p8 = (const bf16x8*)(vb + (size_t)off * CD);
        bf16x8 v0 = p8[0], v1 = p8[1];
        float w = wo.x;
#pragma unroll
        for (int j = 0; j < 8; j++) acc[j] += (float)v0[j] * w;
#pragma unroll
        for (int j = 0; j < 8; j++) acc[8 + j] += (float)v1[j] * w;
    }
    bf16x8 o0, o1;
#pragma unroll
    for (int j = 0; j < 8; j++) { o0[j] = (bf16_t)acc[j]; o1[j] = (bf16_t)acc[8 + j]; }
    bf16x8* dst = (bf16x8*)(samp + (q0g + q) * CD + h * 32 + sh * 16);
    dst[0] = o0;
    dst[1] = o1;
}

// ---- GEMM3: D[c'][n] = WoT[c'][:] . samp[n][:] ; vectorized LDS-transposed epilogue ----
__global__ __launch_bounds__(256, 2) void gemm_out(const bf16_t* __restrict__ X,   // WoT [256][256]
                                                   const bf16_t* __restrict__ Y,   // samp [51200][256]
                                                   const float* __restrict__ bout,
                                                   const float* __restrict__ query,
                                                   const float* __restrict__ value,
                                                   const float* __restrict__ pe,
                                                   float* __restrict__ out) {
    __shared__ __align__(16) char smem[32768];
    bf16_t* lx = (bf16_t*)smem;
    bf16_t* ly = (bf16_t*)(smem + 16384);
    float* tile = (float*)smem;                 // epilogue overlay: [64][128] f32
    int m0 = blockIdx.y * 128;   // c'
    int n0 = blockIdx.x * 128;   // n_glob
    int tid = threadIdx.x, wv = tid >> 6, ln = tid & 63;
    f32x4 acc[4][4] = {};
    int wr = (wv >> 1) * 64, wc = (wv & 1) * 64;
    for (int kt = 0; kt < 4; ++kt) {
#pragma unroll
        for (int q8 = 0; q8 < 4; ++q8) {
            int q = wv * 4 + q8;
            int row = q * 8 + (ln >> 3);
            int jj = (ln & 7) ^ (row & 7);
            gload_lds16((const char*)X + ((size_t)(m0 + row)) * 512 + (size_t)kt * 128 + jj * 16,
                        (char*)lx + q * 1024);
            gload_lds16((const char*)Y + ((size_t)(n0 + row)) * 512 + (size_t)kt * 128 + jj * 16,
                        (char*)ly + q * 1024);
        }
        __syncthreads();
#pragma unroll
        for (int ks = 0; ks < 2; ++ks) {
            bf16x8 xa[4], yb[4];
#pragma unroll
            for (int i = 0; i < 4; i++) {
                int m = wr + i * 16 + (ln & 15);
                int ch = (ks * 4 + (ln >> 4)) ^ (m & 7);
                xa[i] = *(const bf16x8*)((const char*)lx + m * 128 + ch * 16);
                int n = wc + i * 16 + (ln & 15);
                int cn = (ks * 4 + (ln >> 4)) ^ (n & 7);
                yb[i] = *(const bf16x8*)((const char*)ly + n * 128 + cn * 16);
            }
#pragma unroll
            for (int i = 0; i < 4; i++)
#pragma unroll
                for (int j = 0; j < 4; j++)
                    acc[i][j] = __builtin_amdgcn_mfma_f32_16x16x32_bf16(xa[i], yb[j], acc[i][j], 0, 0, 0);
        }
        __syncthreads();
    }
    int b = n0 / NQ;
    int nb = n0 - b * NQ;
    const float* qp = query + (size_t)b * CD * NQ;
    const float* vp = value + (size_t)b * CD * NQ;
    float* o0 = out + (size_t)b * CD * NQ;
    float* o1 = out + OUT_HALF + (size_t)b * CD * NQ;
#pragma unroll
    for (int pass = 0; pass < 2; ++pass) {
        if ((wv >> 1) == pass) {
#pragma unroll
            for (int i = 0; i < 4; i++)
#pragma unroll
                for (int j = 0; j < 4; j++) {
                    int c = wc + j * 16 + (ln & 15);
#pragma unroll
                    for (int rg = 0; rg < 4; rg++) {
                        int r = i * 16 + (ln >> 4) * 4 + rg;
                        tile[r * 128 + c] = acc[i][j][rg] + bout[m0 + pass * 64 + r];
                    }
                }
        }
        __syncthreads();
        int g4 = (ln & 31) * 4;
        int rb = wv * 16 + (ln >> 5);
#pragma unroll
        for (int jj = 0; jj < 8; ++jj) {
            int r = rb + jj * 2;
            int crow = m0 + pass * 64 + r;
            size_t off = (size_t)crow * NQ + nb + g4;
            f32x4 tv = *(const f32x4*)&tile[r * 128 + g4];
            f32x4 qv = *(const f32x4*)(qp + off);
            f32x4 pv = *(const f32x4*)(pe + off);
            f32x4 vv = *(const f32x4*)(vp + off);
            f32x4 o1v = tv + qv + pv;
            *(f32x4*)(o1 + off) = o1v;
            *(f32x4*)(o0 + off) = o1v + vv;
        }
        __syncthreads();
    }
}

extern "C" void kernel_launch(void* const* d_in, const int* in_sizes, int n_in,
                              void* d_out, int out_size, void* d_ws, size_t ws_size,
                              hipStream_t stream) {
    const float* query   = (const float*)d_in[0];
    const float* value   = (const float*)d_in[1];
    const float* W_value = (const float*)d_in[2];
    const float* b_value = (const float*)d_in[3];
    const float* W_off   = (const float*)d_in[4];
    const float* b_off   = (const float*)d_in[5];
    const float* W_attn  = (const float*)d_in[6];
    const float* b_attn  = (const float*)d_in[7];
    const float* W_out   = (const float*)d_in[8];
    const float* b_out   = (const float*)d_in[9];
    float* out = (float*)d_out;
    char* ws = (char*)d_ws;

    float*  pe    = (float*)(ws + 0);              //  6,553,600
    bf16_t* WvT   = (bf16_t*)(ws + 6553600);       //    131,072
    bf16_t* WoT   = (bf16_t*)(ws + 6684672);       //    131,072
    bf16_t* WoaT  = (bf16_t*)(ws + 6815744);       //     49,152
    bf16_t* vprojB= (bf16_t*)(ws + 6864896);       // 26,214,400
    f16_t*  oaH   = (f16_t*)(ws + 33079296);       //  9,830,400
    bf16_t* samp  = (bf16_t*)(ws + 42909696);      // 26,214,400  (total ~69.1 MB)

    pe_kernel<<<(CD * NQ + 255) / 256, 256, 0, stream>>>(pe);
    wprep_kernel<<<256, 256, 0, stream>>>(W_value, W_off, W_attn, W_out, WvT, WoaT, WoT);
    gemm_vproj<<<dim3(400, 2), 256, 0, stream>>>(value, WvT, b_value, vprojB);
    gemm_oa<<<dim3(400), 256, 0, stream>>>(query, WoaT, b_off, b_attn, oaH);
    sample_kernel<<<3200, 256, 0, stream>>>(oaH, vprojB, samp);
    gemm_out<<<dim3(400, 2), 256, 0, stream>>>(WoT, samp, b_out, query, value, pe, out);
}

// Round 6
// 121.553 us; speedup vs baseline: 2.4403x; 1.1286x over previous
//
#include <hip/hip_runtime.h>
#include <hip/hip_bf16.h>
#include <stdint.h>

#define HH 80
#define WW 80
#define NQ 6400        // H*W
#define CD 256         // embed dim
#define BB 8
#define OUT_HALF 13107200   // B*C*H*W
#define PE_NEG 0.0719557841560639f   // ln(10000)/128

typedef __attribute__((ext_vector_type(4))) float f32x4;
typedef __bf16 bf16_t;
typedef __attribute__((ext_vector_type(8))) __bf16 bf16x8;
typedef __attribute__((ext_vector_type(4))) __bf16 bf16x4;
typedef _Float16 f16_t;
typedef __attribute__((ext_vector_type(8))) _Float16 f16x8;

using gp1_t = const __attribute__((address_space(1))) void*;
using lp3_t = __attribute__((address_space(3))) void*;

__device__ __forceinline__ void gload_lds16(const void* g, void* l) {
    __builtin_amdgcn_global_load_lds((gp1_t)g, (lp3_t)l, 16, 0, 0);
}

// ---------------- PE table: pe[c][n], f32 (consumed by gemm_out epilogue) ----------------
__global__ __launch_bounds__(256) void pe_kernel(float* __restrict__ pe) {
    int idx = blockIdx.x * 256 + threadIdx.x;
    if (idx >= CD * NQ) return;
    int c = idx / NQ, n = idx % NQ;
    int h = n / WW, w = n % WW;
    int k = c >> 2;
    float d = __expf((float)(2 * k) * -PE_NEG);
    float arg = ((c & 2) ? (float)(h + 1) : (float)(w + 1)) * d;
    float sv, cv;
    __sincosf(arg, &sv, &cv);
    pe[idx] = (c & 1) ? cv : sv;
}

// ---------------- weight transposes -> bf16, rows = output col, K-contig ----------------
__global__ __launch_bounds__(256) void wprep_kernel(const float* __restrict__ Wv,
                                                    const float* __restrict__ Woff,
                                                    const float* __restrict__ Wattn,
                                                    const float* __restrict__ Wout,
                                                    bf16_t* __restrict__ WvT,
                                                    bf16_t* __restrict__ WoaT,
                                                    bf16_t* __restrict__ WoT) {
    int idx = blockIdx.x * 256 + threadIdx.x;
    if (idx < 65536) {
        int cp = idx >> 8, c = idx & 255;
        WvT[idx] = (bf16_t)Wv[c * 256 + cp];
        WoT[idx] = (bf16_t)Wout[c * 256 + cp];
    }
    if (idx < 96 * 256) {
        int j = idx >> 8, c = idx & 255;
        WoaT[idx] = (bf16_t)(j < 64 ? Woff[c * 64 + j] : Wattn[c * 32 + (j - 64)]);
    }
}

// ================= GEMM cores =================
// B-operand (weights): LDS rows of 128 B (8×16B chunks), XOR-swizzled chunk^(row&7),
//   staged via gload_lds with inverse-swizzled global source.
// A-operand (activations, [c][n] f32 in memory): reg-staged LDS transpose into
//   [n][k] bf16 tile with row stride 144 B (aligned b128 frags; reads 2-way=free).

// ---- GEMM1: vproj[n][c'] = (value^T)[n][:] . WvT[c'][:] + b_value[c']  (bf16 out) ----
__global__ __launch_bounds__(256, 3) void gemm_vproj(const float* __restrict__ V,   // [b][c][n] f32
                                                     const bf16_t* __restrict__ Y,  // WvT [c'][c]
                                                     const float* __restrict__ bias,
                                                     bf16_t* __restrict__ D) {
    __shared__ __align__(16) bf16_t lx[128 * 72];   // [n][k] stride 72 elems = 144 B
    __shared__ __align__(16) bf16_t ly[128 * 64];
    int m0 = blockIdx.x * 128;        // global n rows (across batches; 50 blocks/batch)
    int c0 = blockIdx.y * 128;        // c' tile
    int b = m0 / NQ, nloc = m0 % NQ;
    const float* src = V + (size_t)b * CD * NQ + nloc;
    int tid = threadIdx.x, wv = tid >> 6, ln = tid & 63;
    f32x4 acc[4][4] = {};
    int wr = (wv >> 1) * 64, wc = (wv & 1) * 64;
    int nl = tid & 31;
    for (int kt = 0; kt < 4; ++kt) {
        // B stage
#pragma unroll
        for (int q8 = 0; q8 < 4; ++q8) {
            int q = wv * 4 + q8;
            int row = q * 8 + (ln >> 3);
            int jj = (ln & 7) ^ (row & 7);
            gload_lds16((const char*)Y + ((size_t)(c0 + row)) * 512 + (size_t)kt * 128 + jj * 16,
                        (char*)ly + q * 1024);
        }
        // A stage: k-pair transpose
#pragma unroll
        for (int i = 0; i < 4; ++i) {
            int kp = (tid >> 5) + i * 8;          // 0..31
            int k = kp * 2;
            const float* s0 = src + (size_t)(kt * 64 + k) * NQ;
#pragma unroll
            for (int l = 0; l < 4; ++l) {
                int n = nl + 32 * l;
                float v0 = s0[n];
                float v1 = s0[NQ + n];
                union { bf16_t h[2]; uint32_t u; } pk;
                pk.h[0] = (bf16_t)v0; pk.h[1] = (bf16_t)v1;
                *(uint32_t*)((char*)lx + n * 144 + k * 2) = pk.u;
            }
        }
        __syncthreads();
#pragma unroll
        for (int ks = 0; ks < 2; ++ks) {
            bf16x8 xa[4], yb[4];
#pragma unroll
            for (int i = 0; i < 4; i++) {
                int m = wr + i * 16 + (ln & 15);
                xa[i] = *(const bf16x8*)((const char*)lx + m * 144 + ks * 64 + (ln >> 4) * 16);
                int n = wc + i * 16 + (ln & 15);
                int cn = (ks * 4 + (ln >> 4)) ^ (n & 7);
                yb[i] = *(const bf16x8*)((const char*)ly + n * 128 + cn * 16);
            }
#pragma unroll
            for (int i = 0; i < 4; i++)
#pragma unroll
                for (int j = 0; j < 4; j++)
                    acc[i][j] = __builtin_amdgcn_mfma_f32_16x16x32_bf16(xa[i], yb[j], acc[i][j], 0, 0, 0);
        }
        __syncthreads();
    }
#pragma unroll
    for (int i = 0; i < 4; i++)
#pragma unroll
        for (int j = 0; j < 4; j++) {
            int col = c0 + wc + j * 16 + (ln & 15);
            float bv = bias[col];
#pragma unroll
            for (int rg = 0; rg < 4; rg++) {
                int row = m0 + wr + i * 16 + (ln >> 4) * 4 + rg;
                D[(size_t)row * 256 + col] = (bf16_t)(acc[i][j][rg] + bv);
            }
        }
}

// ---- GEMM2: oa[n][j] = (query+PE)^T[n][:] . WoaT[j][:] + bias_j  (f16 out, N=96) ----
__global__ __launch_bounds__(256, 3) void gemm_oa(const float* __restrict__ Q,    // [b][c][n] f32
                                                  const bf16_t* __restrict__ Y,   // WoaT [j][c]
                                                  const float* __restrict__ boff,
                                                  const float* __restrict__ battn,
                                                  f16_t* __restrict__ D) {
    __shared__ __align__(16) bf16_t lx[128 * 72];
    __shared__ __align__(16) bf16_t ly[96 * 64];
    int m0 = blockIdx.x * 128;
    int b = m0 / NQ, nloc = m0 % NQ;
    const float* src = Q + (size_t)b * CD * NQ + nloc;
    int tid = threadIdx.x, wv = tid >> 6, ln = tid & 63;
    f32x4 acc[2][6] = {};
    int nl = tid & 31;
    for (int kt = 0; kt < 4; ++kt) {
#pragma unroll
        for (int q3 = 0; q3 < 3; ++q3) {
            int q = wv * 3 + q3;
            int row = q * 8 + (ln >> 3);
            int jj = (ln & 7) ^ (row & 7);
            gload_lds16((const char*)Y + ((size_t)row) * 512 + (size_t)kt * 128 + jj * 16,
                        (char*)ly + q * 1024);
        }
        // A stage with inline PE: rows c (even -> sin) and c+1 (odd -> cos) share arg
#pragma unroll
        for (int i = 0; i < 4; ++i) {
            int kp = (tid >> 5) + i * 8;
            int k = kp * 2;
            int c = kt * 64 + k;
            float d = __expf((float)(2 * (c >> 2)) * -PE_NEG);
            const float* s0 = src + (size_t)c * NQ;
#pragma unroll
            for (int l = 0; l < 4; ++l) {
                int n = nl + 32 * l;
                int p = nloc + n;
                int h = p / WW, w = p - h * WW;
                float pos = (c & 2) ? (float)(h + 1) : (float)(w + 1);
                float sv, cv;
                __sincosf(pos * d, &sv, &cv);
                float v0 = s0[n] + sv;
                float v1 = s0[NQ + n] + cv;
                union { bf16_t hh[2]; uint32_t u; } pk;
                pk.hh[0] = (bf16_t)v0; pk.hh[1] = (bf16_t)v1;
                *(uint32_t*)((char*)lx + n * 144 + k * 2) = pk.u;
            }
        }
        __syncthreads();
#pragma unroll
        for (int ks = 0; ks < 2; ++ks) {
            bf16x8 xa[2], yb[6];
#pragma unroll
            for (int i = 0; i < 2; i++) {
                int m = wv * 32 + i * 16 + (ln & 15);
                xa[i] = *(const bf16x8*)((const char*)lx + m * 144 + ks * 64 + (ln >> 4) * 16);
            }
#pragma unroll
            for (int j = 0; j < 6; j++) {
                int n = j * 16 + (ln & 15);
                int cn = (ks * 4 + (ln >> 4)) ^ (n & 7);
                yb[j] = *(const bf16x8*)((const char*)ly + n * 128 + cn * 16);
            }
#pragma unroll
            for (int i = 0; i < 2; i++)
#pragma unroll
                for (int j = 0; j < 6; j++)
                    acc[i][j] = __builtin_amdgcn_mfma_f32_16x16x32_bf16(xa[i], yb[j], acc[i][j], 0, 0, 0);
        }
        __syncthreads();
    }
#pragma unroll
    for (int i = 0; i < 2; i++)
#pragma unroll
        for (int j = 0; j < 6; j++) {
            int col = j * 16 + (ln & 15);
            float bv = col < 64 ? boff[col] : battn[col - 64];
#pragma unroll
            for (int rg = 0; rg < 4; rg++) {
                int row = m0 + wv * 32 + i * 16 + (ln >> 4) * 4 + rg;
                D[(size_t)row * 96 + col] = (f16_t)(acc[i][j][rg] + bv);
            }
        }
}

// ---- sampling v3: 16 queries/block (grid 3200), XCD-swizzled (batch = bid&7).
//      Phase0: oa f16x8 loads -> LDS. Phase1: 128 thr, one (q,h) each: softmax+16 (w,idx).
//      Phase2: 256 thr = (q,h,half): 16 corners x 2 bf16x8 gathers, 16 f32 acc. ----
__global__ __launch_bounds__(256) void sample_kernel(const f16_t* __restrict__ oa,
                                                     const bf16_t* __restrict__ vp,
                                                     bf16_t* __restrict__ samp) {
    __shared__ float s[16][100];          // padded
    __shared__ float2 swo[16][8][17];     // [q][h][p*4+corner], padded
    int t = threadIdx.x;
    int bid = blockIdx.x;                 // 3200 = 8 batches * 400
    int b = bid & 7;
    int nq0 = (bid >> 3) * 16;            // local query base within batch
    size_t q0g = (size_t)b * NQ + nq0;    // global query base
    // phase 0: load 16x96 f16 -> f32 LDS
    if (t < 192) {
        int q = t / 12, e = (t % 12) * 8;
        f16x8 v = *(const f16x8*)(oa + (q0g + q) * 96 + e);
#pragma unroll
        for (int j = 0; j < 8; j++) s[q][e + j] = (float)v[j];
    }
    __syncthreads();
    // phase 1: one (q,h) per thread, t < 128
    if (t < 128) {
        int q = t >> 3, h = t & 7;
        int n = nq0 + q;
        const float* sq = s[q];
        float l0 = sq[64 + h * 4 + 0], l1 = sq[64 + h * 4 + 1];
        float l2 = sq[64 + h * 4 + 2], l3 = sq[64 + h * 4 + 3];
        float mx = fmaxf(fmaxf(l0, l1), fmaxf(l2, l3));
        float e0 = __expf(l0 - mx), e1 = __expf(l1 - mx), e2 = __expf(l2 - mx), e3 = __expf(l3 - mx);
        float inv = 1.f / (e0 + e1 + e2 + e3);
        float aw[4] = {e0 * inv, e1 * inv, e2 * inv, e3 * inv};
        float xb = (float)(n % WW) * (80.f / 79.f) - 0.5f;
        float yb = (float)(n / WW) * (80.f / 79.f) - 0.5f;
#pragma unroll
        for (int p = 0; p < 4; p++) {
            float x = xb + sq[h * 8 + p * 2];
            float y = yb + sq[h * 8 + p * 2 + 1];
            float x0f = floorf(x), y0f = floorf(y);
            float wx = x - x0f, wy = y - y0f;
            int ix = (int)x0f, iy = (int)y0f;
            bool vx0 = (unsigned)ix < (unsigned)WW, vx1 = (unsigned)(ix + 1) < (unsigned)WW;
            bool vy0 = (unsigned)iy < (unsigned)HH, vy1 = (unsigned)(iy + 1) < (unsigned)HH;
            int cx0 = min(max(ix, 0), WW - 1), cx1 = min(max(ix + 1, 0), WW - 1);
            int cy0 = min(max(iy, 0), HH - 1), cy1 = min(max(iy + 1, 0), HH - 1);
            float ap = aw[p];
            float w00 = (vx0 && vy0) ? ap * (1.f - wx) * (1.f - wy) : 0.f;
            float w10 = (vx1 && vy0) ? ap * wx * (1.f - wy) : 0.f;
            float w01 = (vx0 && vy1) ? ap * (1.f - wx) * wy : 0.f;
            float w11 = (vx1 && vy1) ? ap * wx * wy : 0.f;
            swo[q][h][p * 4 + 0] = make_float2(w00, __int_as_float(cy0 * WW + cx0));
            swo[q][h][p * 4 + 1] = make_float2(w10, __int_as_float(cy0 * WW + cx1));
            swo[q][h][p * 4 + 2] = make_float2(w01, __int_as_float(cy1 * WW + cx0));
            swo[q][h][p * 4 + 3] = make_float2(w11, __int_as_float(cy1 * WW + cx1));
        }
    }
    __syncthreads();
    // phase 2: (q, h, half): 16 channels each
    int q = t >> 4, h = (t >> 1) & 7, sh = t & 1;
    const bf16_t* vb = vp + (size_t)b * NQ * CD + h * 32 + sh * 16;
    float acc[16];
#pragma unroll
    for (int j = 0; j < 16; j++) acc[j] = 0.f;
#pragma unroll
    for (int pc = 0; pc < 16; ++pc) {
        float2 wo = swo[q][h][pc];
        int off = __float_as_int(wo.y);
        const bf16x8* p8 = (const bf16x8*)(vb + (size_t)off * CD);
        bf16x8 v0 = p8[0], v1 = p8[1];
        float w = wo.x;
#pragma unroll
        for (int j = 0; j < 8; j++) acc[j] += (float)v0[j] * w;
#pragma unroll
        for (int j = 0; j < 8; j++) acc[8 + j] += (float)v1[j] * w;
    }
    bf16x8 o0, o1;
#pragma unroll
    for (int j = 0; j < 8; j++) { o0[j] = (bf16_t)acc[j]; o1[j] = (bf16_t)acc[8 + j]; }
    bf16x8* dst = (bf16x8*)(samp + (q0g + q) * CD + h * 32 + sh * 16);
    dst[0] = o0;
    dst[1] = o1;
}

// ---- GEMM3: D[c'][n] = WoT[c'][:] . samp[n][:] ; vectorized LDS-transposed epilogue ----
__global__ __launch_bounds__(256, 4) void gemm_out(const bf16_t* __restrict__ X,   // WoT [256][256]
                                                   const bf16_t* __restrict__ Y,   // samp [51200][256]
                                                   const float* __restrict__ bout,
                                                   const float* __restrict__ query,
                                                   const float* __restrict__ value,
                                                   const float* __restrict__ pe,
                                                   float* __restrict__ out) {
    __shared__ __align__(16) char smem[32768];
    bf16_t* lx = (bf16_t*)smem;
    bf16_t* ly = (bf16_t*)(smem + 16384);
    float* tile = (float*)smem;                 // epilogue overlay: [64][128] f32
    int m0 = blockIdx.y * 128;   // c'
    int n0 = blockIdx.x * 128;   // n_glob
    int tid = threadIdx.x, wv = tid >> 6, ln = tid & 63;
    f32x4 acc[4][4] = {};
    int wr = (wv >> 1) * 64, wc = (wv & 1) * 64;
    for (int kt = 0; kt < 4; ++kt) {
#pragma unroll
        for (int q8 = 0; q8 < 4; ++q8) {
            int q = wv * 4 + q8;
            int row = q * 8 + (ln >> 3);
            int jj = (ln & 7) ^ (row & 7);
            gload_lds16((const char*)X + ((size_t)(m0 + row)) * 512 + (size_t)kt * 128 + jj * 16,
                        (char*)lx + q * 1024);
            gload_lds16((const char*)Y + ((size_t)(n0 + row)) * 512 + (size_t)kt * 128 + jj * 16,
                        (char*)ly + q * 1024);
        }
        __syncthreads();
#pragma unroll
        for (int ks = 0; ks < 2; ++ks) {
            bf16x8 xa[4], yb[4];
#pragma unroll
            for (int i = 0; i < 4; i++) {
                int m = wr + i * 16 + (ln & 15);
                int ch = (ks * 4 + (ln >> 4)) ^ (m & 7);
                xa[i] = *(const bf16x8*)((const char*)lx + m * 128 + ch * 16);
                int n = wc + i * 16 + (ln & 15);
                int cn = (ks * 4 + (ln >> 4)) ^ (n & 7);
                yb[i] = *(const bf16x8*)((const char*)ly + n * 128 + cn * 16);
            }
#pragma unroll
            for (int i = 0; i < 4; i++)
#pragma unroll
                for (int j = 0; j < 4; j++)
                    acc[i][j] = __builtin_amdgcn_mfma_f32_16x16x32_bf16(xa[i], yb[j], acc[i][j], 0, 0, 0);
        }
        __syncthreads();
    }
    int b = n0 / NQ;
    int nb = n0 - b * NQ;
    const float* qp = query + (size_t)b * CD * NQ;
    const float* vp = value + (size_t)b * CD * NQ;
    float* o0 = out + (size_t)b * CD * NQ;
    float* o1 = out + OUT_HALF + (size_t)b * CD * NQ;
#pragma unroll
    for (int pass = 0; pass < 2; ++pass) {
        if ((wv >> 1) == pass) {
#pragma unroll
            for (int i = 0; i < 4; i++)
#pragma unroll
                for (int j = 0; j < 4; j++) {
                    int c = wc + j * 16 + (ln & 15);
#pragma unroll
                    for (int rg = 0; rg < 4; rg++) {
                        int r = i * 16 + (ln >> 4) * 4 + rg;
                        tile[r * 128 + c] = acc[i][j][rg] + bout[m0 + pass * 64 + r];
                    }
                }
        }
        __syncthreads();
        int g4 = (ln & 31) * 4;
        int rb = wv * 16 + (ln >> 5);
#pragma unroll
        for (int jj = 0; jj < 8; ++jj) {
            int r = rb + jj * 2;
            int crow = m0 + pass * 64 + r;
            size_t off = (size_t)crow * NQ + nb + g4;
            f32x4 tv = *(const f32x4*)&tile[r * 128 + g4];
            f32x4 qv = *(const f32x4*)(qp + off);
            f32x4 pv = *(const f32x4*)(pe + off);
            f32x4 vv = *(const f32x4*)(vp + off);
            f32x4 o1v = tv + qv + pv;
            *(f32x4*)(o1 + off) = o1v;
            *(f32x4*)(o0 + off) = o1v + vv;
        }
        __syncthreads();
    }
}

extern "C" void kernel_launch(void* const* d_in, const int* in_sizes, int n_in,
                              void* d_out, int out_size, void* d_ws, size_t ws_size,
                              hipStream_t stream) {
    const float* query   = (const float*)d_in[0];
    const float* value   = (const float*)d_in[1];
    const float* W_value = (const float*)d_in[2];
    const float* b_value = (const float*)d_in[3];
    const float* W_off   = (const float*)d_in[4];
    const float* b_off   = (const float*)d_in[5];
    const float* W_attn  = (const float*)d_in[6];
    const float* b_attn  = (const float*)d_in[7];
    const float* W_out   = (const float*)d_in[8];
    const float* b_out   = (const float*)d_in[9];
    float* out = (float*)d_out;
    char* ws = (char*)d_ws;

    float*  pe    = (float*)(ws + 0);              //  6,553,600
    bf16_t* WvT   = (bf16_t*)(ws + 6553600);       //    131,072
    bf16_t* WoT   = (bf16_t*)(ws + 6684672);       //    131,072
    bf16_t* WoaT  = (bf16_t*)(ws + 6815744);       //     49,152
    bf16_t* vprojB= (bf16_t*)(ws + 6864896);       // 26,214,400
    f16_t*  oaH   = (f16_t*)(ws + 33079296);       //  9,830,400
    bf16_t* samp  = (bf16_t*)(ws + 42909696);      // 26,214,400  (total ~69.1 MB)

    pe_kernel<<<(CD * NQ + 255) / 256, 256, 0, stream>>>(pe);
    wprep_kernel<<<256, 256, 0, stream>>>(W_value, W_off, W_attn, W_out, WvT, WoaT, WoT);
    gemm_vproj<<<dim3(400, 2), 256, 0, stream>>>(value, WvT, b_value, vprojB);
    gemm_oa<<<dim3(400), 256, 0, stream>>>(query, WoaT, b_off, b_attn, oaH);
    sample_kernel<<<3200, 256, 0, stream>>>(oaH, vprojB, samp);
    gemm_out<<<dim3(400, 2), 256, 0, stream>>>(WoT, samp, b_out, query, value, pe, out);
}

// Round 7
// 110.086 us; speedup vs baseline: 2.6945x; 1.1042x over previous
//
#include <hip/hip_runtime.h>
#include <hip/hip_bf16.h>
#include <stdint.h>

#define HH 80
#define WW 80
#define NQ 6400        // H*W
#define CD 256         // embed dim
#define BB 8
#define OUT_HALF 13107200   // B*C*H*W
#define PE_NEG 0.0719557841560639f   // ln(10000)/128

typedef __attribute__((ext_vector_type(4))) float f32x4;
typedef __bf16 bf16_t;
typedef __attribute__((ext_vector_type(8))) __bf16 bf16x8;
typedef _Float16 f16_t;

using gp1_t = const __attribute__((address_space(1))) void*;
using lp3_t = __attribute__((address_space(3))) void*;

__device__ __forceinline__ void gload_lds16(const void* g, void* l) {
    __builtin_amdgcn_global_load_lds((gp1_t)g, (lp3_t)l, 16, 0, 0);
}

// ---------------- weight transposes -> bf16, rows = output col, K-contig ----------------
__global__ __launch_bounds__(256) void wprep_kernel(const float* __restrict__ Wv,
                                                    const float* __restrict__ Woff,
                                                    const float* __restrict__ Wattn,
                                                    const float* __restrict__ Wout,
                                                    bf16_t* __restrict__ WvT,
                                                    bf16_t* __restrict__ WoaT,
                                                    bf16_t* __restrict__ WoT) {
    int idx = blockIdx.x * 256 + threadIdx.x;
    if (idx < 65536) {
        int cp = idx >> 8, c = idx & 255;
        WvT[idx] = (bf16_t)Wv[c * 256 + cp];
        WoT[idx] = (bf16_t)Wout[c * 256 + cp];
    }
    if (idx < 96 * 256) {
        int j = idx >> 8, c = idx & 255;
        WoaT[idx] = (bf16_t)(j < 64 ? Woff[c * 64 + j] : Wattn[c * 32 + (j - 64)]);
    }
}

// ---- GEMM1: vproj[n][c'] = (value^T)[n][:] . WvT[c'][:] + b_value[c']  (bf16 out) ----
__global__ __launch_bounds__(256, 3) void gemm_vproj(const float* __restrict__ V,   // [b][c][n] f32
                                                     const bf16_t* __restrict__ Y,  // WvT [c'][c]
                                                     const float* __restrict__ bias,
                                                     bf16_t* __restrict__ D) {
    __shared__ __align__(16) bf16_t lx[128 * 72];   // [n][k] stride 72 elems = 144 B
    __shared__ __align__(16) bf16_t ly[128 * 64];
    int m0 = blockIdx.x * 128;
    int c0 = blockIdx.y * 128;
    int b = m0 / NQ, nloc = m0 % NQ;
    const float* src = V + (size_t)b * CD * NQ + nloc;
    int tid = threadIdx.x, wv = tid >> 6, ln = tid & 63;
    f32x4 acc[4][4] = {};
    int wr = (wv >> 1) * 64, wc = (wv & 1) * 64;
    int nl = tid & 31;
    for (int kt = 0; kt < 4; ++kt) {
#pragma unroll
        for (int q8 = 0; q8 < 4; ++q8) {
            int q = wv * 4 + q8;
            int row = q * 8 + (ln >> 3);
            int jj = (ln & 7) ^ (row & 7);
            gload_lds16((const char*)Y + ((size_t)(c0 + row)) * 512 + (size_t)kt * 128 + jj * 16,
                        (char*)ly + q * 1024);
        }
#pragma unroll
        for (int i = 0; i < 4; ++i) {
            int kp = (tid >> 5) + i * 8;
            int k = kp * 2;
            const float* s0 = src + (size_t)(kt * 64 + k) * NQ;
#pragma unroll
            for (int l = 0; l < 4; ++l) {
                int n = nl + 32 * l;
                float v0 = s0[n];
                float v1 = s0[NQ + n];
                union { bf16_t h[2]; uint32_t u; } pk;
                pk.h[0] = (bf16_t)v0; pk.h[1] = (bf16_t)v1;
                *(uint32_t*)((char*)lx + n * 144 + k * 2) = pk.u;
            }
        }
        __syncthreads();
#pragma unroll
        for (int ks = 0; ks < 2; ++ks) {
            bf16x8 xa[4], yb[4];
#pragma unroll
            for (int i = 0; i < 4; i++) {
                int m = wr + i * 16 + (ln & 15);
                xa[i] = *(const bf16x8*)((const char*)lx + m * 144 + ks * 64 + (ln >> 4) * 16);
                int n = wc + i * 16 + (ln & 15);
                int cn = (ks * 4 + (ln >> 4)) ^ (n & 7);
                yb[i] = *(const bf16x8*)((const char*)ly + n * 128 + cn * 16);
            }
#pragma unroll
            for (int i = 0; i < 4; i++)
#pragma unroll
                for (int j = 0; j < 4; j++)
                    acc[i][j] = __builtin_amdgcn_mfma_f32_16x16x32_bf16(xa[i], yb[j], acc[i][j], 0, 0, 0);
        }
        __syncthreads();
    }
#pragma unroll
    for (int i = 0; i < 4; i++)
#pragma unroll
        for (int j = 0; j < 4; j++) {
            int col = c0 + wc + j * 16 + (ln & 15);
            float bv = bias[col];
#pragma unroll
            for (int rg = 0; rg < 4; rg++) {
                int row = m0 + wr + i * 16 + (ln >> 4) * 4 + rg;
                D[(size_t)row * 256 + col] = (bf16_t)(acc[i][j][rg] + bv);
            }
        }
}

// ---- FUSED: oa GEMM (query+PE -> offsets/logits, f16 in LDS) + deformable sampling ----
// grid 400 = 8 batches (bid&7, XCD-local) x 50 tiles of 128 queries.
__global__ __launch_bounds__(256, 2) void oa_sample(const float* __restrict__ Q,    // [b][c][n] f32
                                                    const bf16_t* __restrict__ Y,   // WoaT [j][c]
                                                    const float* __restrict__ boff,
                                                    const float* __restrict__ battn,
                                                    const bf16_t* __restrict__ vp,  // vproj [b*NQ][256]
                                                    bf16_t* __restrict__ samp) {
    __shared__ __align__(16) bf16_t lx[128 * 72];   // 18,432 B
    __shared__ __align__(16) bf16_t ly[96 * 64];    // 12,288 B
    __shared__ f16_t oaT[128][100];                 // 25,600 B  [q_loc][j]
    int bid = blockIdx.x;
    int b = bid & 7;
    int nloc = (bid >> 3) * 128;          // local query base
    int m0 = b * NQ + nloc;               // global query base
    const float* src = Q + (size_t)b * CD * NQ + nloc;
    int tid = threadIdx.x, wv = tid >> 6, ln = tid & 63;
    f32x4 acc[2][6] = {};
    int nl = tid & 31;
    for (int kt = 0; kt < 4; ++kt) {
#pragma unroll
        for (int q3 = 0; q3 < 3; ++q3) {
            int q = wv * 3 + q3;
            int row = q * 8 + (ln >> 3);
            int jj = (ln & 7) ^ (row & 7);
            gload_lds16((const char*)Y + ((size_t)row) * 512 + (size_t)kt * 128 + jj * 16,
                        (char*)ly + q * 1024);
        }
        // A stage with inline PE
#pragma unroll
        for (int i = 0; i < 4; ++i) {
            int kp = (tid >> 5) + i * 8;
            int k = kp * 2;
            int c = kt * 64 + k;
            float d = __expf((float)(2 * (c >> 2)) * -PE_NEG);
            const float* s0 = src + (size_t)c * NQ;
#pragma unroll
            for (int l = 0; l < 4; ++l) {
                int n = nl + 32 * l;
                int p = nloc + n;
                int h = p / WW, w = p - h * WW;
                float pos = (c & 2) ? (float)(h + 1) : (float)(w + 1);
                float sv, cv;
                __sincosf(pos * d, &sv, &cv);
                float v0 = s0[n] + sv;
                float v1 = s0[NQ + n] + cv;
                union { bf16_t hh[2]; uint32_t u; } pk;
                pk.hh[0] = (bf16_t)v0; pk.hh[1] = (bf16_t)v1;
                *(uint32_t*)((char*)lx + n * 144 + k * 2) = pk.u;
            }
        }
        __syncthreads();
#pragma unroll
        for (int ks = 0; ks < 2; ++ks) {
            bf16x8 xa[2], yb[6];
#pragma unroll
            for (int i = 0; i < 2; i++) {
                int m = wv * 32 + i * 16 + (ln & 15);
                xa[i] = *(const bf16x8*)((const char*)lx + m * 144 + ks * 64 + (ln >> 4) * 16);
            }
#pragma unroll
            for (int j = 0; j < 6; j++) {
                int n = j * 16 + (ln & 15);
                int cn = (ks * 4 + (ln >> 4)) ^ (n & 7);
                yb[j] = *(const bf16x8*)((const char*)ly + n * 128 + cn * 16);
            }
#pragma unroll
            for (int i = 0; i < 2; i++)
#pragma unroll
                for (int j = 0; j < 6; j++)
                    acc[i][j] = __builtin_amdgcn_mfma_f32_16x16x32_bf16(xa[i], yb[j], acc[i][j], 0, 0, 0);
        }
        __syncthreads();
    }
    // GEMM epilogue -> LDS f16 tile
#pragma unroll
    for (int i = 0; i < 2; i++)
#pragma unroll
        for (int j = 0; j < 6; j++) {
            int col = j * 16 + (ln & 15);
            float bv = col < 64 ? boff[col] : battn[col - 64];
#pragma unroll
            for (int rg = 0; rg < 4; rg++) {
                int rloc = wv * 32 + i * 16 + (ln >> 4) * 4 + rg;
                oaT[rloc][col] = (f16_t)(acc[i][j][rg] + bv);
            }
        }
    __syncthreads();
    // ---- sampling: 8 rounds x 256 units (16 q x 8 h x 2 halves); weights recomputed
    //      by each half-pair thread (no swo LDS, no extra syncs) ----
    int h = (tid >> 1) & 7, sh = tid & 1;
    const bf16_t* vb = vp + (size_t)b * NQ * CD + h * 32 + sh * 16;
#pragma unroll
    for (int rnd = 0; rnd < 8; ++rnd) {
        int q = rnd * 16 + (tid >> 4);
        int n = nloc + q;
        const f16_t* sq = oaT[q];
        float l0 = (float)sq[64 + h * 4 + 0], l1 = (float)sq[64 + h * 4 + 1];
        float l2 = (float)sq[64 + h * 4 + 2], l3 = (float)sq[64 + h * 4 + 3];
        float mx = fmaxf(fmaxf(l0, l1), fmaxf(l2, l3));
        float e0 = __expf(l0 - mx), e1 = __expf(l1 - mx), e2 = __expf(l2 - mx), e3 = __expf(l3 - mx);
        float inv = 1.f / (e0 + e1 + e2 + e3);
        float aw[4] = {e0 * inv, e1 * inv, e2 * inv, e3 * inv};
        float xb = (float)(n % WW) * (80.f / 79.f) - 0.5f;
        float yb = (float)(n / WW) * (80.f / 79.f) - 0.5f;
        float wgt[16];
        int idx[16];
#pragma unroll
        for (int p = 0; p < 4; p++) {
            float x = xb + (float)sq[h * 8 + p * 2];
            float y = yb + (float)sq[h * 8 + p * 2 + 1];
            float x0f = floorf(x), y0f = floorf(y);
            float wx = x - x0f, wy = y - y0f;
            int ix = (int)x0f, iy = (int)y0f;
            bool vx0 = (unsigned)ix < (unsigned)WW, vx1 = (unsigned)(ix + 1) < (unsigned)WW;
            bool vy0 = (unsigned)iy < (unsigned)HH, vy1 = (unsigned)(iy + 1) < (unsigned)HH;
            int cx0 = min(max(ix, 0), WW - 1), cx1 = min(max(ix + 1, 0), WW - 1);
            int cy0 = min(max(iy, 0), HH - 1), cy1 = min(max(iy + 1, 0), HH - 1);
            float ap = aw[p];
            wgt[p * 4 + 0] = (vx0 && vy0) ? ap * (1.f - wx) * (1.f - wy) : 0.f;
            wgt[p * 4 + 1] = (vx1 && vy0) ? ap * wx * (1.f - wy) : 0.f;
            wgt[p * 4 + 2] = (vx0 && vy1) ? ap * (1.f - wx) * wy : 0.f;
            wgt[p * 4 + 3] = (vx1 && vy1) ? ap * wx * wy : 0.f;
            idx[p * 4 + 0] = cy0 * WW + cx0;
            idx[p * 4 + 1] = cy0 * WW + cx1;
            idx[p * 4 + 2] = cy1 * WW + cx0;
            idx[p * 4 + 3] = cy1 * WW + cx1;
        }
        float fac[16];
#pragma unroll
        for (int j = 0; j < 16; j++) fac[j] = 0.f;
#pragma unroll
        for (int pc = 0; pc < 16; ++pc) {
            const bf16x8* p8 = (const bf16x8*)(vb + (size_t)idx[pc] * CD);
            bf16x8 v0 = p8[0], v1 = p8[1];
            float w = wgt[pc];
#pragma unroll
            for (int j = 0; j < 8; j++) fac[j] += (float)v0[j] * w;
#pragma unroll
            for (int j = 0; j < 8; j++) fac[8 + j] += (float)v1[j] * w;
        }
        bf16x8 o0, o1;
#pragma unroll
        for (int j = 0; j < 8; j++) { o0[j] = (bf16_t)fac[j]; o1[j] = (bf16_t)fac[8 + j]; }
        bf16x8* dst = (bf16x8*)(samp + (size_t)(m0 + q) * CD + h * 32 + sh * 16);
        dst[0] = o0;
        dst[1] = o1;
    }
}

// ---- GEMM3: D[c'][n] = WoT[c'][:] . samp[n][:] ; LDS-transposed epilogue, inline PE ----
__global__ __launch_bounds__(256, 4) void gemm_out(const bf16_t* __restrict__ X,   // WoT [256][256]
                                                   const bf16_t* __restrict__ Y,   // samp [51200][256]
                                                   const float* __restrict__ bout,
                                                   const float* __restrict__ query,
                                                   const float* __restrict__ value,
                                                   float* __restrict__ out) {
    __shared__ __align__(16) char smem[32768];
    bf16_t* lx = (bf16_t*)smem;
    bf16_t* ly = (bf16_t*)(smem + 16384);
    float* tile = (float*)smem;                 // epilogue overlay: [64][128] f32
    int m0 = blockIdx.y * 128;   // c'
    int n0 = blockIdx.x * 128;   // n_glob
    int tid = threadIdx.x, wv = tid >> 6, ln = tid & 63;
    f32x4 acc[4][4] = {};
    int wr = (wv >> 1) * 64, wc = (wv & 1) * 64;
    for (int kt = 0; kt < 4; ++kt) {
#pragma unroll
        for (int q8 = 0; q8 < 4; ++q8) {
            int q = wv * 4 + q8;
            int row = q * 8 + (ln >> 3);
            int jj = (ln & 7) ^ (row & 7);
            gload_lds16((const char*)X + ((size_t)(m0 + row)) * 512 + (size_t)kt * 128 + jj * 16,
                        (char*)lx + q * 1024);
            gload_lds16((const char*)Y + ((size_t)(n0 + row)) * 512 + (size_t)kt * 128 + jj * 16,
                        (char*)ly + q * 1024);
        }
        __syncthreads();
#pragma unroll
        for (int ks = 0; ks < 2; ++ks) {
            bf16x8 xa[4], yb[4];
#pragma unroll
            for (int i = 0; i < 4; i++) {
                int m = wr + i * 16 + (ln & 15);
                int ch = (ks * 4 + (ln >> 4)) ^ (m & 7);
                xa[i] = *(const bf16x8*)((const char*)lx + m * 128 + ch * 16);
                int n = wc + i * 16 + (ln & 15);
                int cn = (ks * 4 + (ln >> 4)) ^ (n & 7);
                yb[i] = *(const bf16x8*)((const char*)ly + n * 128 + cn * 16);
            }
#pragma unroll
            for (int i = 0; i < 4; i++)
#pragma unroll
                for (int j = 0; j < 4; j++)
                    acc[i][j] = __builtin_amdgcn_mfma_f32_16x16x32_bf16(xa[i], yb[j], acc[i][j], 0, 0, 0);
        }
        __syncthreads();
    }
    int b = n0 / NQ;
    int nb = n0 - b * NQ;
    const float* qp = query + (size_t)b * CD * NQ;
    const float* vp = value + (size_t)b * CD * NQ;
    float* o0 = out + (size_t)b * CD * NQ;
    float* o1 = out + OUT_HALF + (size_t)b * CD * NQ;
#pragma unroll
    for (int pass = 0; pass < 2; ++pass) {
        if ((wv >> 1) == pass) {
#pragma unroll
            for (int i = 0; i < 4; i++)
#pragma unroll
                for (int j = 0; j < 4; j++) {
                    int c = wc + j * 16 + (ln & 15);
#pragma unroll
                    for (int rg = 0; rg < 4; rg++) {
                        int r = i * 16 + (ln >> 4) * 4 + rg;
                        tile[r * 128 + c] = acc[i][j][rg] + bout[m0 + pass * 64 + r];
                    }
                }
        }
        __syncthreads();
        int g4 = (ln & 31) * 4;
        int rb = wv * 16 + (ln >> 5);
#pragma unroll
        for (int jj = 0; jj < 8; ++jj) {
            int r = rb + jj * 2;
            int crow = m0 + pass * 64 + r;
            size_t off = (size_t)crow * NQ + nb + g4;
            f32x4 tv = *(const f32x4*)&tile[r * 128 + g4];
            f32x4 qv = *(const f32x4*)(qp + off);
            f32x4 vv = *(const f32x4*)(vp + off);
            // inline PE recompute: pe[crow][nb+g4+e]
            float d = __expf((float)(2 * (crow >> 2)) * -PE_NEG);
            bool useY = (crow & 2) != 0, odd = (crow & 1) != 0;
            f32x4 pv;
#pragma unroll
            for (int e = 0; e < 4; ++e) {
                int n = nb + g4 + e;
                int hh = n / WW, ww = n - hh * WW;
                float pos = useY ? (float)(hh + 1) : (float)(ww + 1);
                float sv, cv;
                __sincosf(pos * d, &sv, &cv);
                pv[e] = odd ? cv : sv;
            }
            f32x4 o1v = tv + qv + pv;
            *(f32x4*)(o1 + off) = o1v;
            *(f32x4*)(o0 + off) = o1v + vv;
        }
        __syncthreads();
    }
}

extern "C" void kernel_launch(void* const* d_in, const int* in_sizes, int n_in,
                              void* d_out, int out_size, void* d_ws, size_t ws_size,
                              hipStream_t stream) {
    const float* query   = (const float*)d_in[0];
    const float* value   = (const float*)d_in[1];
    const float* W_value = (const float*)d_in[2];
    const float* b_value = (const float*)d_in[3];
    const float* W_off   = (const float*)d_in[4];
    const float* b_off   = (const float*)d_in[5];
    const float* W_attn  = (const float*)d_in[6];
    const float* b_attn  = (const float*)d_in[7];
    const float* W_out   = (const float*)d_in[8];
    const float* b_out   = (const float*)d_in[9];
    float* out = (float*)d_out;
    char* ws = (char*)d_ws;

    bf16_t* WvT   = (bf16_t*)(ws + 0);             //    131,072
    bf16_t* WoT   = (bf16_t*)(ws + 131072);        //    131,072
    bf16_t* WoaT  = (bf16_t*)(ws + 262144);        //     49,152
    bf16_t* vprojB= (bf16_t*)(ws + 311296);        // 26,214,400
    bf16_t* samp  = (bf16_t*)(ws + 26525696);      // 26,214,400  (total ~52.7 MB)

    wprep_kernel<<<256, 256, 0, stream>>>(W_value, W_off, W_attn, W_out, WvT, WoaT, WoT);
    gemm_vproj<<<dim3(400, 2), 256, 0, stream>>>(value, WvT, b_value, vprojB);
    oa_sample<<<400, 256, 0, stream>>>(query, WoaT, b_off, b_attn, vprojB, samp);
    gemm_out<<<dim3(400, 2), 256, 0, stream>>>(WoT, samp, b_out, query, value, out);
}